// Round 1
// baseline (2319.416 us; speedup 1.0000x reference)
//
#include <hip/hip_runtime.h>
#include <math.h>

#define NTOK 4096
#define DIM  1024
#define HEADS 16
#define HD   64
#define NEG_BIG (-3.402823466e38f)

// ---------------- RMSNorm: one block per row ----------------
__global__ __launch_bounds__(256) void k_rmsnorm(const float* __restrict__ emb,
                                                 const float* __restrict__ w,
                                                 float* __restrict__ xn) {
    int row = blockIdx.x;
    int t = threadIdx.x;
    const float4* e4 = (const float4*)(emb + (size_t)row * DIM);
    float4 x = e4[t];
    float ss = x.x*x.x + x.y*x.y + x.z*x.z + x.w*x.w;
    #pragma unroll
    for (int off = 32; off > 0; off >>= 1) ss += __shfl_down(ss, off);
    __shared__ float red[4];
    int lane = t & 63, wid = t >> 6;
    if (lane == 0) red[wid] = ss;
    __syncthreads();
    float tot = red[0] + red[1] + red[2] + red[3];
    float scale = rsqrtf(tot * (1.0f / (float)DIM) + 1e-6f);
    float4 wv = ((const float4*)w)[t];
    float4 o;
    o.x = x.x * scale * wv.x;
    o.y = x.y * scale * wv.y;
    o.z = x.z * scale * wv.z;
    o.w = x.w * scale * wv.w;
    ((float4*)(xn + (size_t)row * DIM))[t] = o;
}

// ---------------- prep: seq_end (mask bound) + RoPE tables ----------------
__global__ void k_prep(const int* __restrict__ seq_ids, const int* __restrict__ gidx,
                       int* __restrict__ kv_end, float* __restrict__ sin_t,
                       float* __restrict__ cos_t) {
    int n = blockIdx.x * blockDim.x + threadIdx.x;
    if (n >= NTOK) return;
    int id = seq_ids[n];
    // upper_bound over sorted ids: first index > n whose id differs
    int lo = n + 1, hi = NTOK;
    while (lo < hi) {
        int mid = (lo + hi) >> 1;
        if (seq_ids[mid] == id) lo = mid + 1; else hi = mid;
    }
    kv_end[n] = lo;  // union of causal and same-block == j < seq_end[n]
    double pos = (double)gidx[n];
    const double lt = 13.122363377404328;  // log(500000)
    for (int f = 0; f < 32; f++) {
        double ang = pos * exp(-(double)f * (1.0 / 32.0) * lt);
        sin_t[n * 32 + f] = (float)sin(ang);
        cos_t[n * 32 + f] = (float)cos(ang);
    }
}

// ---------------- QKV projection GEMM + clip + RoPE ----------------
// out[n,o] = sum_d xn[n,d] * W[o,d]; out tile 64x64, BK=32, 4x4 micro-tile
__global__ __launch_bounds__(256) void k_proj(const float* __restrict__ xn,
                                              const float* __restrict__ Wq,
                                              const float* __restrict__ Wk,
                                              const float* __restrict__ Wv,
                                              const float* __restrict__ sin_t,
                                              const float* __restrict__ cos_t,
                                              float* __restrict__ qo,
                                              float* __restrict__ ko,
                                              float* __restrict__ vo) {
    int bm = blockIdx.x, h = blockIdx.y, z = blockIdx.z;
    const float* W = (z == 0) ? Wq : (z == 1) ? Wk : Wv;
    float* out = (z == 0) ? qo : (z == 1) ? ko : vo;
    __shared__ float xs[64][33];
    __shared__ float ws[64][33];
    __shared__ float ts[64][65];
    int t = threadIdx.x;
    int tx = t & 15, ty = t >> 4;
    float acc[4][4] = {};
    for (int kt = 0; kt < DIM; kt += 32) {
        #pragma unroll
        for (int r = 0; r < 2; r++) {
            int idx = t * 2 + r;
            int row = idx >> 3, c4 = (idx & 7) << 2;
            float4 a = *(const float4*)(xn + (size_t)(bm * 64 + row) * DIM + kt + c4);
            xs[row][c4+0] = a.x; xs[row][c4+1] = a.y; xs[row][c4+2] = a.z; xs[row][c4+3] = a.w;
            float4 b = *(const float4*)(W + (size_t)(h * 64 + row) * DIM + kt + c4);
            ws[row][c4+0] = b.x; ws[row][c4+1] = b.y; ws[row][c4+2] = b.z; ws[row][c4+3] = b.w;
        }
        __syncthreads();
        #pragma unroll
        for (int kk = 0; kk < 32; kk++) {
            float a[4], b[4];
            #pragma unroll
            for (int r = 0; r < 4; r++) a[r] = xs[ty*4+r][kk];
            #pragma unroll
            for (int c = 0; c < 4; c++) b[c] = ws[tx*4+c][kk];
            #pragma unroll
            for (int r = 0; r < 4; r++)
                #pragma unroll
                for (int c = 0; c < 4; c++) acc[r][c] = fmaf(a[r], b[c], acc[r][c]);
        }
        __syncthreads();
    }
    // clip
    #pragma unroll
    for (int r = 0; r < 4; r++)
        #pragma unroll
        for (int c = 0; c < 4; c++)
            acc[r][c] = fminf(fmaxf(acc[r][c], -8.0f), 8.0f);

    if (z < 2) {
        // stage tile for RoPE pair exchange (d <-> d+-32)
        #pragma unroll
        for (int r = 0; r < 4; r++)
            #pragma unroll
            for (int c = 0; c < 4; c++)
                ts[ty*4+r][tx*4+c] = acc[r][c];
        __syncthreads();
        #pragma unroll
        for (int r = 0; r < 4; r++) {
            int i = ty*4 + r;
            int n = bm*64 + i;
            #pragma unroll
            for (int c = 0; c < 4; c++) {
                int d = tx*4 + c;
                int f = d & 31;
                float s = sin_t[n*32 + f], co = cos_t[n*32 + f];
                float val = acc[r][c];
                float partner = (d < 32) ? ts[i][d+32] : ts[i][d-32];
                float res = val * co + ((d < 32) ? -partner : partner) * s;
                out[((size_t)h * NTOK + n) * HD + d] = res;
            }
        }
    } else {
        #pragma unroll
        for (int r = 0; r < 4; r++)
            #pragma unroll
            for (int c = 0; c < 4; c++)
                out[((size_t)h * NTOK + bm*64 + ty*4+r) * HD + tx*4+c] = acc[r][c];
    }
}

// ---------------- flash attention, extended-causal mask ----------------
__global__ __launch_bounds__(256) void k_attn(const float* __restrict__ q,
                                              const float* __restrict__ k,
                                              const float* __restrict__ v,
                                              const int* __restrict__ kv_end,
                                              float* __restrict__ ao) {
    int qt = blockIdx.x, h = blockIdx.y;
    __shared__ float Qs[64][65];
    __shared__ float Ks[64][65];
    __shared__ float Vs[64][65];
    __shared__ float Ss[64][65];
    __shared__ float mS[64], lS[64], aS[64];
    __shared__ int keS[64];
    int t = threadIdx.x;
    const float* qh = q + ((size_t)h * NTOK + qt * 64) * HD;
    #pragma unroll
    for (int r = 0; r < 4; r++) {
        int idx = t + r * 256;
        int row = idx >> 4, c4 = (idx & 15) << 2;
        float4 a = *(const float4*)(qh + row * HD + c4);
        Qs[row][c4+0]=a.x; Qs[row][c4+1]=a.y; Qs[row][c4+2]=a.z; Qs[row][c4+3]=a.w;
    }
    if (t < 64) { keS[t] = kv_end[qt*64 + t]; mS[t] = NEG_BIG; lS[t] = 0.f; }
    int kmax = kv_end[qt*64 + 63];  // seq_end monotone (sorted ids) -> tile max
    float acc[4][4] = {};
    int i0 = (t >> 4) * 4;   // 4 query rows
    int x0 = (t & 15) * 4;   // 4 key cols (S phase) / 4 dims (PV phase)
    __syncthreads();
    for (int jt = 0; jt < kmax; jt += 64) {
        const float* kh = k + ((size_t)h * NTOK + jt) * HD;
        const float* vh = v + ((size_t)h * NTOK + jt) * HD;
        #pragma unroll
        for (int r = 0; r < 4; r++) {
            int idx = t + r * 256;
            int row = idx >> 4, c4 = (idx & 15) << 2;
            float4 a = *(const float4*)(kh + row * HD + c4);
            Ks[row][c4+0]=a.x; Ks[row][c4+1]=a.y; Ks[row][c4+2]=a.z; Ks[row][c4+3]=a.w;
            float4 b = *(const float4*)(vh + row * HD + c4);
            Vs[row][c4+0]=b.x; Vs[row][c4+1]=b.y; Vs[row][c4+2]=b.z; Vs[row][c4+3]=b.w;
        }
        __syncthreads();
        float sa[4][4] = {};
        #pragma unroll 16
        for (int kk = 0; kk < 64; kk++) {
            float a[4], b[4];
            #pragma unroll
            for (int r = 0; r < 4; r++) a[r] = Qs[i0+r][kk];
            #pragma unroll
            for (int c = 0; c < 4; c++) b[c] = Ks[x0+c][kk];
            #pragma unroll
            for (int r = 0; r < 4; r++)
                #pragma unroll
                for (int c = 0; c < 4; c++) sa[r][c] = fmaf(a[r], b[c], sa[r][c]);
        }
        #pragma unroll
        for (int r = 0; r < 4; r++)
            #pragma unroll
            for (int c = 0; c < 4; c++) {
                int j = jt + x0 + c;
                float s = sa[r][c] * 0.125f;
                Ss[i0+r][x0+c] = (j < keS[i0+r]) ? s : NEG_BIG;
            }
        __syncthreads();
        if (t < 64) {  // online softmax row update
            float m0 = mS[t], mx = m0;
            for (int j = 0; j < 64; j++) mx = fmaxf(mx, Ss[t][j]);
            float al = __expf(m0 - mx);
            float sum = 0.f;
            for (int j = 0; j < 64; j++) { float p = __expf(Ss[t][j] - mx); Ss[t][j] = p; sum += p; }
            lS[t] = lS[t] * al + sum;
            mS[t] = mx; aS[t] = al;
        }
        __syncthreads();
        float al[4];
        #pragma unroll
        for (int r = 0; r < 4; r++) al[r] = aS[i0+r];
        #pragma unroll
        for (int r = 0; r < 4; r++)
            #pragma unroll
            for (int c = 0; c < 4; c++) acc[r][c] *= al[r];
        #pragma unroll 16
        for (int j = 0; j < 64; j++) {
            float p[4], vv[4];
            #pragma unroll
            for (int r = 0; r < 4; r++) p[r] = Ss[i0+r][j];
            #pragma unroll
            for (int c = 0; c < 4; c++) vv[c] = Vs[j][x0+c];
            #pragma unroll
            for (int r = 0; r < 4; r++)
                #pragma unroll
                for (int c = 0; c < 4; c++) acc[r][c] = fmaf(p[r], vv[c], acc[r][c]);
        }
        __syncthreads();
    }
    float inv[4];
    #pragma unroll
    for (int r = 0; r < 4; r++) inv[r] = 1.0f / lS[i0+r];
    #pragma unroll
    for (int r = 0; r < 4; r++)
        #pragma unroll
        for (int c = 0; c < 4; c++)
            ao[(size_t)(qt*64 + i0 + r) * DIM + h * HD + x0 + c] = acc[r][c] * inv[r];
}

// ---------------- output projection GEMM ----------------
__global__ __launch_bounds__(256) void k_gemm_out(const float* __restrict__ ao,
                                                  const float* __restrict__ Wo,
                                                  float* __restrict__ out) {
    int bm = blockIdx.x, bn = blockIdx.y;
    __shared__ float xs[64][33];
    __shared__ float ws[64][33];
    int t = threadIdx.x;
    int tx = t & 15, ty = t >> 4;
    float acc[4][4] = {};
    for (int kt = 0; kt < DIM; kt += 32) {
        #pragma unroll
        for (int r = 0; r < 2; r++) {
            int idx = t * 2 + r;
            int row = idx >> 3, c4 = (idx & 7) << 2;
            float4 a = *(const float4*)(ao + (size_t)(bm * 64 + row) * DIM + kt + c4);
            xs[row][c4+0] = a.x; xs[row][c4+1] = a.y; xs[row][c4+2] = a.z; xs[row][c4+3] = a.w;
            float4 b = *(const float4*)(Wo + (size_t)(bn * 64 + row) * DIM + kt + c4);
            ws[row][c4+0] = b.x; ws[row][c4+1] = b.y; ws[row][c4+2] = b.z; ws[row][c4+3] = b.w;
        }
        __syncthreads();
        #pragma unroll
        for (int kk = 0; kk < 32; kk++) {
            float a[4], b[4];
            #pragma unroll
            for (int r = 0; r < 4; r++) a[r] = xs[ty*4+r][kk];
            #pragma unroll
            for (int c = 0; c < 4; c++) b[c] = ws[tx*4+c][kk];
            #pragma unroll
            for (int r = 0; r < 4; r++)
                #pragma unroll
                for (int c = 0; c < 4; c++) acc[r][c] = fmaf(a[r], b[c], acc[r][c]);
        }
        __syncthreads();
    }
    #pragma unroll
    for (int r = 0; r < 4; r++)
        #pragma unroll
        for (int c = 0; c < 4; c++)
            out[(size_t)(bm*64 + ty*4+r) * DIM + bn*64 + tx*4+c] = acc[r][c];
}

extern "C" void kernel_launch(void* const* d_in, const int* in_sizes, int n_in,
                              void* d_out, int out_size, void* d_ws, size_t ws_size,
                              hipStream_t stream) {
    const float* emb   = (const float*)d_in[0];
    const float* normw = (const float*)d_in[1];
    const float* Wq    = (const float*)d_in[2];
    const float* Wk    = (const float*)d_in[3];
    const float* Wv    = (const float*)d_in[4];
    const float* Wo    = (const float*)d_in[5];
    const int*   gidx  = (const int*)d_in[7];
    const int*   sids  = (const int*)d_in[8];
    float* out = (float*)d_out;

    float* xn   = (float*)d_ws;                      // [4096][1024]
    float* qb   = xn  + (size_t)NTOK*DIM;            // [16][4096][64]
    float* kb   = qb  + (size_t)HEADS*NTOK*HD;
    float* vb   = kb  + (size_t)HEADS*NTOK*HD;
    float* ao   = vb  + (size_t)HEADS*NTOK*HD;       // [4096][1024]
    float* sint = ao  + (size_t)NTOK*DIM;            // [4096][32]
    float* cost = sint + (size_t)NTOK*32;
    int*   kvend = (int*)(cost + (size_t)NTOK*32);   // [4096]

    hipLaunchKernelGGL(k_rmsnorm, dim3(NTOK), dim3(256), 0, stream, emb, normw, xn);
    hipLaunchKernelGGL(k_prep, dim3((NTOK+255)/256), dim3(256), 0, stream, sids, gidx, kvend, sint, cost);
    hipLaunchKernelGGL(k_proj, dim3(NTOK/64, HEADS, 3), dim3(256), 0, stream,
                       xn, Wq, Wk, Wv, sint, cost, qb, kb, vb);
    hipLaunchKernelGGL(k_attn, dim3(NTOK/64, HEADS), dim3(256), 0, stream, qb, kb, vb, kvend, ao);
    hipLaunchKernelGGL(k_gemm_out, dim3(NTOK/64, DIM/64), dim3(256), 0, stream, ao, Wo, out);
}

// Round 3
// 932.992 us; speedup vs baseline: 2.4860x; 2.4860x over previous
//
#include <hip/hip_runtime.h>
#include <hip/hip_bf16.h>
#include <math.h>

#define NTOK 4096
#define DIM  1024
#define HEADS 16
#define HD   64
#define NEG_BIG (-3.402823466e38f)

typedef __attribute__((ext_vector_type(8))) short bf16x8;
typedef __attribute__((ext_vector_type(4))) float f32x4;

// ---------------- RMSNorm: one block per row ----------------
__global__ __launch_bounds__(256) void k_rmsnorm(const float* __restrict__ emb,
                                                 const float* __restrict__ w,
                                                 float* __restrict__ xn) {
    int row = blockIdx.x;
    int t = threadIdx.x;
    const float4* e4 = (const float4*)(emb + (size_t)row * DIM);
    float4 x = e4[t];
    float ss = x.x*x.x + x.y*x.y + x.z*x.z + x.w*x.w;
    #pragma unroll
    for (int off = 32; off > 0; off >>= 1) ss += __shfl_down(ss, off);
    __shared__ float red[4];
    int lane = t & 63, wid = t >> 6;
    if (lane == 0) red[wid] = ss;
    __syncthreads();
    float tot = red[0] + red[1] + red[2] + red[3];
    float scale = rsqrtf(tot * (1.0f / (float)DIM) + 1e-6f);
    float4 wv = ((const float4*)w)[t];
    float4 o;
    o.x = x.x * scale * wv.x;
    o.y = x.y * scale * wv.y;
    o.z = x.z * scale * wv.z;
    o.w = x.w * scale * wv.w;
    ((float4*)(xn + (size_t)row * DIM))[t] = o;
}

// ---------------- prep: seq_end (mask bound) + RoPE tables ----------------
__global__ void k_prep(const int* __restrict__ seq_ids, const int* __restrict__ gidx,
                       int* __restrict__ kv_end, float* __restrict__ sin_t,
                       float* __restrict__ cos_t) {
    int n = blockIdx.x * blockDim.x + threadIdx.x;
    if (n >= NTOK) return;
    int id = seq_ids[n];
    int lo = n + 1, hi = NTOK;
    while (lo < hi) {
        int mid = (lo + hi) >> 1;
        if (seq_ids[mid] == id) lo = mid + 1; else hi = mid;
    }
    kv_end[n] = lo;  // union of causal and same-block == j < seq_end[n]
    double pos = (double)gidx[n];
    const double lt = 13.122363377404328;  // log(500000)
    for (int f = 0; f < 32; f++) {
        double ang = pos * exp(-(double)f * (1.0 / 32.0) * lt);
        sin_t[n * 32 + f] = (float)sin(ang);
        cos_t[n * 32 + f] = (float)cos(ang);
    }
}

// ---------------- QKV projection GEMM + clip + RoPE (bf16 out) ----------------
__global__ __launch_bounds__(256) void k_proj(const float* __restrict__ xn,
                                              const float* __restrict__ Wq,
                                              const float* __restrict__ Wk,
                                              const float* __restrict__ Wv,
                                              const float* __restrict__ sin_t,
                                              const float* __restrict__ cos_t,
                                              __hip_bfloat16* __restrict__ qo,
                                              __hip_bfloat16* __restrict__ ko,
                                              __hip_bfloat16* __restrict__ vo) {
    int bm = blockIdx.x, h = blockIdx.y, z = blockIdx.z;
    const float* W = (z == 0) ? Wq : (z == 1) ? Wk : Wv;
    __hip_bfloat16* out = (z == 0) ? qo : (z == 1) ? ko : vo;
    __shared__ float xs[64][33];
    __shared__ float ws[64][33];
    __shared__ float ts[64][65];
    int t = threadIdx.x;
    int tx = t & 15, ty = t >> 4;
    float acc[4][4] = {};
    for (int kt = 0; kt < DIM; kt += 32) {
        #pragma unroll
        for (int r = 0; r < 2; r++) {
            int idx = t * 2 + r;
            int row = idx >> 3, c4 = (idx & 7) << 2;
            float4 a = *(const float4*)(xn + (size_t)(bm * 64 + row) * DIM + kt + c4);
            xs[row][c4+0] = a.x; xs[row][c4+1] = a.y; xs[row][c4+2] = a.z; xs[row][c4+3] = a.w;
            float4 b = *(const float4*)(W + (size_t)(h * 64 + row) * DIM + kt + c4);
            ws[row][c4+0] = b.x; ws[row][c4+1] = b.y; ws[row][c4+2] = b.z; ws[row][c4+3] = b.w;
        }
        __syncthreads();
        #pragma unroll
        for (int kk = 0; kk < 32; kk++) {
            float a[4], b[4];
            #pragma unroll
            for (int r = 0; r < 4; r++) a[r] = xs[ty*4+r][kk];
            #pragma unroll
            for (int c = 0; c < 4; c++) b[c] = ws[tx*4+c][kk];
            #pragma unroll
            for (int r = 0; r < 4; r++)
                #pragma unroll
                for (int c = 0; c < 4; c++) acc[r][c] = fmaf(a[r], b[c], acc[r][c]);
        }
        __syncthreads();
    }
    #pragma unroll
    for (int r = 0; r < 4; r++)
        #pragma unroll
        for (int c = 0; c < 4; c++)
            acc[r][c] = fminf(fmaxf(acc[r][c], -8.0f), 8.0f);

    if (z < 2) {
        #pragma unroll
        for (int r = 0; r < 4; r++)
            #pragma unroll
            for (int c = 0; c < 4; c++)
                ts[ty*4+r][tx*4+c] = acc[r][c];
        __syncthreads();
        #pragma unroll
        for (int r = 0; r < 4; r++) {
            int i = ty*4 + r;
            int n = bm*64 + i;
            #pragma unroll
            for (int c = 0; c < 4; c++) {
                int d = tx*4 + c;
                int f = d & 31;
                float s = sin_t[n*32 + f], co = cos_t[n*32 + f];
                float val = acc[r][c];
                float partner = (d < 32) ? ts[i][d+32] : ts[i][d-32];
                float res = val * co + ((d < 32) ? -partner : partner) * s;
                out[((size_t)h * NTOK + n) * HD + d] = __float2bfloat16(res);
            }
        }
    } else {
        #pragma unroll
        for (int r = 0; r < 4; r++)
            #pragma unroll
            for (int c = 0; c < 4; c++)
                out[((size_t)h * NTOK + bm*64 + ty*4+r) * HD + tx*4+c] = __float2bfloat16(acc[r][c]);
    }
}

// ---------------- flash attention, bf16 MFMA ----------------
// 4 waves / block; Q-tile 64 rows; wave w owns rows w*16..w*16+15.
// mfma_f32_16x16x32_bf16: A row=lane&15, k=(lane>>4)*8+j; C/D col=lane&15, row=(lane>>4)*4+reg.
__global__ __launch_bounds__(256) void k_attn(const __hip_bfloat16* __restrict__ qg,
                                              const __hip_bfloat16* __restrict__ kg,
                                              const __hip_bfloat16* __restrict__ vg,
                                              const int* __restrict__ kv_end,
                                              float* __restrict__ ao) {
    int qt = blockIdx.x, h = blockIdx.y;
    int t = threadIdx.x;
    int w = t >> 6, lane = t & 63;
    int lg = lane >> 4, li = lane & 15;

    __shared__ short Ks[64*64];      // [key][hd], XOR-swizzled rows (128B)
    __shared__ short Vt[64*64];      // [dim][key], XOR-swizzled rows
    __shared__ short Ps[4][16*64];   // per-wave P tile, swizzled
    char* KsB = (char*)Ks;
    char* VtB = (char*)Vt;
    char* PsB = (char*)&Ps[w][0];

    // Q fragments straight from global (once)
    const __hip_bfloat16* qh = qg + ((size_t)h*NTOK + (size_t)qt*64)*HD;
    int qrow = w*16 + li;
    bf16x8 qa[2];
    qa[0] = *(const bf16x8*)(qh + qrow*HD + lg*8);
    qa[1] = *(const bf16x8*)(qh + qrow*HD + lg*8 + 32);

    int ke[4];
    #pragma unroll
    for (int r = 0; r < 4; r++) ke[r] = kv_end[qt*64 + w*16 + lg*4 + r];
    int kmax = kv_end[qt*64 + 63];  // ids sorted -> seq_end monotone

    float m[4] = {-1e30f, -1e30f, -1e30f, -1e30f};
    float l[4] = {0.f, 0.f, 0.f, 0.f};
    f32x4 acc_o[4] = {};

    int skey = t >> 2;           // staging: key row 0..63
    int sc0 = (t & 3) * 16;      // staging: 16-elem column chunk

    for (int jt = 0; jt < kmax; jt += 64) {
        // ---- stage K [key][hd] and V^T [dim][key], both swizzled ----
        const __hip_bfloat16* kh = kg + ((size_t)h*NTOK + jt + skey)*HD;
        const __hip_bfloat16* vh = vg + ((size_t)h*NTOK + jt + skey)*HD;
        bf16x8 k0 = *(const bf16x8*)(kh + sc0);
        bf16x8 k1 = *(const bf16x8*)(kh + sc0 + 8);
        bf16x8 v0 = *(const bf16x8*)(vh + sc0);
        bf16x8 v1 = *(const bf16x8*)(vh + sc0 + 8);
        int swz = (skey & 7) << 4;
        *(bf16x8*)(KsB + skey*128 + ((sc0*2) ^ swz)) = k0;
        *(bf16x8*)(KsB + skey*128 + ((sc0*2 + 16) ^ swz)) = k1;
        #pragma unroll
        for (int j = 0; j < 8; j++) {   // transpose V: row=(dim), col=key
            *(short*)(VtB + (sc0+j)*128   + ((skey*2) ^ (j<<4))) = v0[j];
            *(short*)(VtB + (sc0+8+j)*128 + ((skey*2) ^ (j<<4))) = v1[j];
        }
        __syncthreads();

        // ---- S = Q K^T : 4 key-blocks x 2 k-steps ----
        f32x4 sacc[4] = {};
        #pragma unroll
        for (int kb = 0; kb < 4; kb++) {
            int key = kb*16 + li;
            int ksw = (key & 7) << 4;
            bf16x8 kf0 = *(const bf16x8*)(KsB + key*128 + (((lg*8)*2) ^ ksw));
            bf16x8 kf1 = *(const bf16x8*)(KsB + key*128 + (((32 + lg*8)*2) ^ ksw));
            sacc[kb] = __builtin_amdgcn_mfma_f32_16x16x32_bf16(qa[0], kf0, sacc[kb], 0, 0, 0);
            sacc[kb] = __builtin_amdgcn_mfma_f32_16x16x32_bf16(qa[1], kf1, sacc[kb], 0, 0, 0);
        }

        // ---- online softmax (wave-parallel; row r lives on 16 lanes of group lg) ----
        #pragma unroll
        for (int r = 0; r < 4; r++) {
            float sv[4];
            #pragma unroll
            for (int kb = 0; kb < 4; kb++) {
                int j = jt + kb*16 + li;
                float s = sacc[kb][r] * 0.125f;
                sv[kb] = (j < ke[r]) ? s : -1e30f;
            }
            float mx = fmaxf(fmaxf(sv[0], sv[1]), fmaxf(sv[2], sv[3]));
            #pragma unroll
            for (int d = 1; d < 16; d <<= 1) mx = fmaxf(mx, __shfl_xor(mx, d));
            float mn = fmaxf(m[r], mx);
            float al = __expf(m[r] - mn);
            float sum = 0.f;
            #pragma unroll
            for (int kb = 0; kb < 4; kb++) { sv[kb] = __expf(sv[kb] - mn); sum += sv[kb]; }
            #pragma unroll
            for (int d = 1; d < 16; d <<= 1) sum += __shfl_xor(sum, d);
            l[r] = l[r] * al + sum;
            m[r] = mn;
            #pragma unroll
            for (int vb = 0; vb < 4; vb++) acc_o[vb][r] *= al;
            int prow = lg*4 + r;
            int psw = (prow & 7) << 4;
            #pragma unroll
            for (int kb = 0; kb < 4; kb++)
                *(__hip_bfloat16*)(PsB + prow*128 + (((kb*16 + li)*2) ^ psw)) = __float2bfloat16(sv[kb]);
        }

        // wave-internal LDS RAW across lanes: drain, and pin the reads after it
        asm volatile("s_waitcnt lgkmcnt(0)" ::: "memory");
        __builtin_amdgcn_sched_barrier(0);

        // ---- O += P V ----
        bf16x8 pa[2];
        {
            int psw = (li & 7) << 4;
            pa[0] = *(const bf16x8*)(PsB + li*128 + (((lg*8)*2) ^ psw));
            pa[1] = *(const bf16x8*)(PsB + li*128 + (((32 + lg*8)*2) ^ psw));
        }
        #pragma unroll
        for (int vb = 0; vb < 4; vb++) {
            int dim = vb*16 + li;
            int vsw = (dim & 7) << 4;
            bf16x8 vf0 = *(const bf16x8*)(VtB + dim*128 + (((lg*8)*2) ^ vsw));
            bf16x8 vf1 = *(const bf16x8*)(VtB + dim*128 + (((32 + lg*8)*2) ^ vsw));
            acc_o[vb] = __builtin_amdgcn_mfma_f32_16x16x32_bf16(pa[0], vf0, acc_o[vb], 0, 0, 0);
            acc_o[vb] = __builtin_amdgcn_mfma_f32_16x16x32_bf16(pa[1], vf1, acc_o[vb], 0, 0, 0);
        }
        __syncthreads();
    }

    #pragma unroll
    for (int r = 0; r < 4; r++) {
        float inv = 1.0f / l[r];
        int row = qt*64 + w*16 + lg*4 + r;
        #pragma unroll
        for (int vb = 0; vb < 4; vb++)
            ao[(size_t)row*DIM + h*HD + vb*16 + li] = acc_o[vb][r] * inv;
    }
}

// ---------------- output projection GEMM ----------------
__global__ __launch_bounds__(256) void k_gemm_out(const float* __restrict__ ao,
                                                  const float* __restrict__ Wo,
                                                  float* __restrict__ out) {
    int bm = blockIdx.x, bn = blockIdx.y;
    __shared__ float xs[64][33];
    __shared__ float ws[64][33];
    int t = threadIdx.x;
    int tx = t & 15, ty = t >> 4;
    float acc[4][4] = {};
    for (int kt = 0; kt < DIM; kt += 32) {
        #pragma unroll
        for (int r = 0; r < 2; r++) {
            int idx = t * 2 + r;
            int row = idx >> 3, c4 = (idx & 7) << 2;
            float4 a = *(const float4*)(ao + (size_t)(bm * 64 + row) * DIM + kt + c4);
            xs[row][c4+0] = a.x; xs[row][c4+1] = a.y; xs[row][c4+2] = a.z; xs[row][c4+3] = a.w;
            float4 b = *(const float4*)(Wo + (size_t)(bn * 64 + row) * DIM + kt + c4);
            ws[row][c4+0] = b.x; ws[row][c4+1] = b.y; ws[row][c4+2] = b.z; ws[row][c4+3] = b.w;
        }
        __syncthreads();
        #pragma unroll
        for (int kk = 0; kk < 32; kk++) {
            float a[4], b[4];
            #pragma unroll
            for (int r = 0; r < 4; r++) a[r] = xs[ty*4+r][kk];
            #pragma unroll
            for (int c = 0; c < 4; c++) b[c] = ws[tx*4+c][kk];
            #pragma unroll
            for (int r = 0; r < 4; r++)
                #pragma unroll
                for (int c = 0; c < 4; c++) acc[r][c] = fmaf(a[r], b[c], acc[r][c]);
        }
        __syncthreads();
    }
    #pragma unroll
    for (int r = 0; r < 4; r++)
        #pragma unroll
        for (int c = 0; c < 4; c++)
            out[(size_t)(bm*64 + ty*4+r) * DIM + bn*64 + tx*4+c] = acc[r][c];
}

extern "C" void kernel_launch(void* const* d_in, const int* in_sizes, int n_in,
                              void* d_out, int out_size, void* d_ws, size_t ws_size,
                              hipStream_t stream) {
    const float* emb   = (const float*)d_in[0];
    const float* normw = (const float*)d_in[1];
    const float* Wq    = (const float*)d_in[2];
    const float* Wk    = (const float*)d_in[3];
    const float* Wv    = (const float*)d_in[4];
    const float* Wo    = (const float*)d_in[5];
    const int*   gidx  = (const int*)d_in[7];
    const int*   sids  = (const int*)d_in[8];
    float* out = (float*)d_out;

    float* xn   = (float*)d_ws;                          // [4096][1024] f32
    __hip_bfloat16* qb = (__hip_bfloat16*)(xn + (size_t)NTOK*DIM);   // [16][4096][64] bf16
    __hip_bfloat16* kb = qb + (size_t)HEADS*NTOK*HD;
    __hip_bfloat16* vb = kb + (size_t)HEADS*NTOK*HD;
    float* ao   = (float*)(vb + (size_t)HEADS*NTOK*HD);  // [4096][1024] f32
    float* sint = ao + (size_t)NTOK*DIM;                 // [4096][32]
    float* cost = sint + (size_t)NTOK*32;
    int*   kvend = (int*)(cost + (size_t)NTOK*32);       // [4096]

    hipLaunchKernelGGL(k_rmsnorm, dim3(NTOK), dim3(256), 0, stream, emb, normw, xn);
    hipLaunchKernelGGL(k_prep, dim3((NTOK+255)/256), dim3(256), 0, stream, sids, gidx, kvend, sint, cost);
    hipLaunchKernelGGL(k_proj, dim3(NTOK/64, HEADS, 3), dim3(256), 0, stream,
                       xn, Wq, Wk, Wv, sint, cost, qb, kb, vb);
    hipLaunchKernelGGL(k_attn, dim3(NTOK/64, HEADS), dim3(256), 0, stream, qb, kb, vb, kvend, ao);
    hipLaunchKernelGGL(k_gemm_out, dim3(NTOK/64, DIM/64), dim3(256), 0, stream, ao, Wo, out);
}

// Round 4
// 355.101 us; speedup vs baseline: 6.5317x; 2.6274x over previous
//
#include <hip/hip_runtime.h>
#include <hip/hip_bf16.h>
#include <math.h>

#define NTOK 4096
#define DIM  1024
#define HEADS 16
#define HD   64

typedef __attribute__((ext_vector_type(8))) short bf16x8;
typedef __attribute__((ext_vector_type(4))) float f32x4;

// ---------------- RMSNorm: one block per row, bf16 out ----------------
__global__ __launch_bounds__(256) void k_rmsnorm(const float* __restrict__ emb,
                                                 const float* __restrict__ w,
                                                 __hip_bfloat16* __restrict__ xn) {
    int row = blockIdx.x;
    int t = threadIdx.x;
    const float4* e4 = (const float4*)(emb + (size_t)row * DIM);
    float4 x = e4[t];
    float ss = x.x*x.x + x.y*x.y + x.z*x.z + x.w*x.w;
    #pragma unroll
    for (int off = 32; off > 0; off >>= 1) ss += __shfl_down(ss, off);
    __shared__ float red[4];
    int lane = t & 63, wid = t >> 6;
    if (lane == 0) red[wid] = ss;
    __syncthreads();
    float tot = red[0] + red[1] + red[2] + red[3];
    float scale = rsqrtf(tot * (1.0f / (float)DIM) + 1e-6f);
    float4 wv = ((const float4*)w)[t];
    union { __hip_bfloat16 h[4]; uint2 u; } pk;
    pk.h[0] = __float2bfloat16(x.x * scale * wv.x);
    pk.h[1] = __float2bfloat16(x.y * scale * wv.y);
    pk.h[2] = __float2bfloat16(x.z * scale * wv.z);
    pk.h[3] = __float2bfloat16(x.w * scale * wv.w);
    *(uint2*)(xn + (size_t)row * DIM + t * 4) = pk.u;
}

// ---------------- weight f32 -> bf16 ----------------
__global__ __launch_bounds__(256) void k_w2bf(const float* __restrict__ s0, const float* __restrict__ s1,
                                              const float* __restrict__ s2, const float* __restrict__ s3,
                                              __hip_bfloat16* __restrict__ d0, __hip_bfloat16* __restrict__ d1,
                                              __hip_bfloat16* __restrict__ d2, __hip_bfloat16* __restrict__ d3) {
    int z = blockIdx.y;
    const float* s = (z == 0) ? s0 : (z == 1) ? s1 : (z == 2) ? s2 : s3;
    __hip_bfloat16* d = (z == 0) ? d0 : (z == 1) ? d1 : (z == 2) ? d2 : d3;
    size_t i = ((size_t)blockIdx.x * 256 + threadIdx.x) * 4;
    float4 v = *(const float4*)(s + i);
    union { __hip_bfloat16 h[4]; uint2 u; } pk;
    pk.h[0] = __float2bfloat16(v.x);
    pk.h[1] = __float2bfloat16(v.y);
    pk.h[2] = __float2bfloat16(v.z);
    pk.h[3] = __float2bfloat16(v.w);
    *(uint2*)(d + i) = pk.u;
}

// ---------------- prep: seq_end (mask bound) + RoPE tables ----------------
__global__ void k_prep(const int* __restrict__ seq_ids, const int* __restrict__ gidx,
                       int* __restrict__ kv_end, float* __restrict__ sin_t,
                       float* __restrict__ cos_t) {
    int n = blockIdx.x * blockDim.x + threadIdx.x;
    if (n >= NTOK) return;
    int id = seq_ids[n];
    int lo = n + 1, hi = NTOK;
    while (lo < hi) {
        int mid = (lo + hi) >> 1;
        if (seq_ids[mid] == id) lo = mid + 1; else hi = mid;
    }
    kv_end[n] = lo;  // union of causal and same-block == j < seq_end[n]
    double pos = (double)gidx[n];
    const double lt = 13.122363377404328;  // log(500000)
    for (int f = 0; f < 32; f++) {
        double ang = pos * exp(-(double)f * (1.0 / 32.0) * lt);
        sin_t[n * 32 + f] = (float)sin(ang);
        cos_t[n * 32 + f] = (float)cos(ang);
    }
}

// ---------------- shared MFMA GEMM core ----------------
// C[128x128] tile of A(M x K=1024) . B(N x K)^T, A/B bf16 row-major (K contiguous).
// 4 waves (2x2), wave tile 64x64, BK=32, global_load_lds w/ pre-swizzled source,
// XOR-swizzled ds_read (2-way max conflict).
__device__ __forceinline__ void gemm_core(const __hip_bfloat16* __restrict__ A,
                                          const __hip_bfloat16* __restrict__ B,
                                          short* As, short* Bs,
                                          int bm, int bn, f32x4 (&acc)[4][4], int t) {
    int w = t >> 6, l = t & 63;
    int wm = w >> 1, wn = w & 1;
    int li = l & 15, lg = l >> 4;
    int lr = l >> 2, lc = l & 3;
    for (int kt = 0; kt < DIM; kt += 32) {
        #pragma unroll
        for (int i = 0; i < 2; i++) {
            int r = w * 32 + i * 16 + lr;
            int c = lc ^ ((r >> 1) & 3);
            const __hip_bfloat16* ga = A + (size_t)(bm * 128 + r) * DIM + kt + c * 8;
            __builtin_amdgcn_global_load_lds(
                (const __attribute__((address_space(1))) unsigned int*)ga,
                (__attribute__((address_space(3))) unsigned int*)(As + (w * 32 + i * 16) * 32),
                16, 0, 0);
            const __hip_bfloat16* gb = B + (size_t)(bn * 128 + r) * DIM + kt + c * 8;
            __builtin_amdgcn_global_load_lds(
                (const __attribute__((address_space(1))) unsigned int*)gb,
                (__attribute__((address_space(3))) unsigned int*)(Bs + (w * 32 + i * 16) * 32),
                16, 0, 0);
        }
        __syncthreads();
        bf16x8 af[4], bfr[4];
        #pragma unroll
        for (int mb = 0; mb < 4; mb++) {
            int r = wm * 64 + mb * 16 + li;
            af[mb] = *(const bf16x8*)((const char*)As + r * 64 + ((lg ^ ((r >> 1) & 3)) << 4));
        }
        #pragma unroll
        for (int nb = 0; nb < 4; nb++) {
            int r = wn * 64 + nb * 16 + li;
            bfr[nb] = *(const bf16x8*)((const char*)Bs + r * 64 + ((lg ^ ((r >> 1) & 3)) << 4));
        }
        #pragma unroll
        for (int mb = 0; mb < 4; mb++)
            #pragma unroll
            for (int nb = 0; nb < 4; nb++)
                acc[mb][nb] = __builtin_amdgcn_mfma_f32_16x16x32_bf16(af[mb], bfr[nb], acc[mb][nb], 0, 0, 0);
        __syncthreads();
    }
}

// ---------------- QKV projection + clip + RoPE (all MFMA) ----------------
__global__ __launch_bounds__(256) void k_qkv(const __hip_bfloat16* __restrict__ xn,
                                             const __hip_bfloat16* __restrict__ wq,
                                             const __hip_bfloat16* __restrict__ wk,
                                             const __hip_bfloat16* __restrict__ wv,
                                             const float* __restrict__ sin_t,
                                             const float* __restrict__ cos_t,
                                             __hip_bfloat16* __restrict__ qo,
                                             __hip_bfloat16* __restrict__ ko,
                                             __hip_bfloat16* __restrict__ vo) {
    __shared__ alignas(16) short As[128 * 32];
    __shared__ alignas(16) short Bs[128 * 32];
    int bm = blockIdx.x, bn = blockIdx.y, z = blockIdx.z;
    const __hip_bfloat16* W = (z == 0) ? wq : (z == 1) ? wk : wv;
    __hip_bfloat16* out = (z == 0) ? qo : (z == 1) ? ko : vo;
    int t = threadIdx.x;
    f32x4 acc[4][4] = {};
    gemm_core(xn, W, As, Bs, bm, bn, acc, t);

    int w = t >> 6, l = t & 63;
    int wm = w >> 1, wn = w & 1;
    int li = l & 15, lg = l >> 4;
    // clip +-8
    #pragma unroll
    for (int mb = 0; mb < 4; mb++)
        #pragma unroll
        for (int nb = 0; nb < 4; nb++)
            #pragma unroll
            for (int r = 0; r < 4; r++)
                acc[mb][nb][r] = fminf(fmaxf(acc[mb][nb][r], -8.0f), 8.0f);

    int h = bn * 2 + wn;   // wave owns one full head (64 cols)
    if (z < 2) {
        // RoPE in-register: partner d+-32 = fragment nb^2, same lane.
        #pragma unroll
        for (int mb = 0; mb < 4; mb++) {
            #pragma unroll
            for (int r = 0; r < 4; r++) {
                int n = bm * 128 + wm * 64 + mb * 16 + lg * 4 + r;
                float s0 = sin_t[n * 32 + li],      c0 = cos_t[n * 32 + li];
                float s1 = sin_t[n * 32 + 16 + li], c1 = cos_t[n * 32 + 16 + li];
                float v0 = acc[mb][0][r], v1 = acc[mb][1][r];
                float v2 = acc[mb][2][r], v3 = acc[mb][3][r];
                __hip_bfloat16* op = out + ((size_t)h * NTOK + n) * HD + li;
                op[0]  = __float2bfloat16(v0 * c0 - v2 * s0);
                op[16] = __float2bfloat16(v1 * c1 - v3 * s1);
                op[32] = __float2bfloat16(v2 * c0 + v0 * s0);
                op[48] = __float2bfloat16(v3 * c1 + v1 * s1);
            }
        }
    } else {
        #pragma unroll
        for (int mb = 0; mb < 4; mb++) {
            #pragma unroll
            for (int r = 0; r < 4; r++) {
                int n = bm * 128 + wm * 64 + mb * 16 + lg * 4 + r;
                __hip_bfloat16* op = out + ((size_t)h * NTOK + n) * HD + li;
                op[0]  = __float2bfloat16(acc[mb][0][r]);
                op[16] = __float2bfloat16(acc[mb][1][r]);
                op[32] = __float2bfloat16(acc[mb][2][r]);
                op[48] = __float2bfloat16(acc[mb][3][r]);
            }
        }
    }
}

// ---------------- output projection (MFMA), f32 out ----------------
__global__ __launch_bounds__(256) void k_wo(const __hip_bfloat16* __restrict__ ao,
                                            const __hip_bfloat16* __restrict__ wo,
                                            float* __restrict__ out) {
    __shared__ alignas(16) short As[128 * 32];
    __shared__ alignas(16) short Bs[128 * 32];
    int bm = blockIdx.x, bn = blockIdx.y;
    int t = threadIdx.x;
    f32x4 acc[4][4] = {};
    gemm_core(ao, wo, As, Bs, bm, bn, acc, t);

    int w = t >> 6, l = t & 63;
    int wm = w >> 1, wn = w & 1;
    int li = l & 15, lg = l >> 4;
    #pragma unroll
    for (int mb = 0; mb < 4; mb++) {
        #pragma unroll
        for (int r = 0; r < 4; r++) {
            int n = bm * 128 + wm * 64 + mb * 16 + lg * 4 + r;
            float* op = out + (size_t)n * DIM + bn * 128 + wn * 64 + li;
            op[0]  = acc[mb][0][r];
            op[16] = acc[mb][1][r];
            op[32] = acc[mb][2][r];
            op[48] = acc[mb][3][r];
        }
    }
}

// ---------------- flash attention, bf16 MFMA (ao out now bf16) ----------------
__global__ __launch_bounds__(256) void k_attn(const __hip_bfloat16* __restrict__ qg,
                                              const __hip_bfloat16* __restrict__ kg,
                                              const __hip_bfloat16* __restrict__ vg,
                                              const int* __restrict__ kv_end,
                                              __hip_bfloat16* __restrict__ ao) {
    int qt = blockIdx.x, h = blockIdx.y;
    int t = threadIdx.x;
    int w = t >> 6, lane = t & 63;
    int lg = lane >> 4, li = lane & 15;

    __shared__ short Ks[64*64];      // [key][hd], XOR-swizzled rows (128B)
    __shared__ short Vt[64*64];      // [dim][key], XOR-swizzled rows
    __shared__ short Ps[4][16*64];   // per-wave P tile, swizzled
    char* KsB = (char*)Ks;
    char* VtB = (char*)Vt;
    char* PsB = (char*)&Ps[w][0];

    const __hip_bfloat16* qh = qg + ((size_t)h*NTOK + (size_t)qt*64)*HD;
    int qrow = w*16 + li;
    bf16x8 qa[2];
    qa[0] = *(const bf16x8*)(qh + qrow*HD + lg*8);
    qa[1] = *(const bf16x8*)(qh + qrow*HD + lg*8 + 32);

    int ke[4];
    #pragma unroll
    for (int r = 0; r < 4; r++) ke[r] = kv_end[qt*64 + w*16 + lg*4 + r];
    int kmax = kv_end[qt*64 + 63];  // ids sorted -> seq_end monotone

    float m[4] = {-1e30f, -1e30f, -1e30f, -1e30f};
    float l[4] = {0.f, 0.f, 0.f, 0.f};
    f32x4 acc_o[4] = {};

    int skey = t >> 2;
    int sc0 = (t & 3) * 16;

    for (int jt = 0; jt < kmax; jt += 64) {
        const __hip_bfloat16* kh = kg + ((size_t)h*NTOK + jt + skey)*HD;
        const __hip_bfloat16* vh = vg + ((size_t)h*NTOK + jt + skey)*HD;
        bf16x8 k0 = *(const bf16x8*)(kh + sc0);
        bf16x8 k1 = *(const bf16x8*)(kh + sc0 + 8);
        bf16x8 v0 = *(const bf16x8*)(vh + sc0);
        bf16x8 v1 = *(const bf16x8*)(vh + sc0 + 8);
        int swz = (skey & 7) << 4;
        *(bf16x8*)(KsB + skey*128 + ((sc0*2) ^ swz)) = k0;
        *(bf16x8*)(KsB + skey*128 + ((sc0*2 + 16) ^ swz)) = k1;
        #pragma unroll
        for (int j = 0; j < 8; j++) {
            *(short*)(VtB + (sc0+j)*128   + ((skey*2) ^ (j<<4))) = v0[j];
            *(short*)(VtB + (sc0+8+j)*128 + ((skey*2) ^ (j<<4))) = v1[j];
        }
        __syncthreads();

        f32x4 sacc[4] = {};
        #pragma unroll
        for (int kb = 0; kb < 4; kb++) {
            int key = kb*16 + li;
            int ksw = (key & 7) << 4;
            bf16x8 kf0 = *(const bf16x8*)(KsB + key*128 + (((lg*8)*2) ^ ksw));
            bf16x8 kf1 = *(const bf16x8*)(KsB + key*128 + (((32 + lg*8)*2) ^ ksw));
            sacc[kb] = __builtin_amdgcn_mfma_f32_16x16x32_bf16(qa[0], kf0, sacc[kb], 0, 0, 0);
            sacc[kb] = __builtin_amdgcn_mfma_f32_16x16x32_bf16(qa[1], kf1, sacc[kb], 0, 0, 0);
        }

        #pragma unroll
        for (int r = 0; r < 4; r++) {
            float sv[4];
            #pragma unroll
            for (int kb = 0; kb < 4; kb++) {
                int j = jt + kb*16 + li;
                float s = sacc[kb][r] * 0.125f;
                sv[kb] = (j < ke[r]) ? s : -1e30f;
            }
            float mx = fmaxf(fmaxf(sv[0], sv[1]), fmaxf(sv[2], sv[3]));
            #pragma unroll
            for (int d = 1; d < 16; d <<= 1) mx = fmaxf(mx, __shfl_xor(mx, d));
            float mn = fmaxf(m[r], mx);
            float al = __expf(m[r] - mn);
            float sum = 0.f;
            #pragma unroll
            for (int kb = 0; kb < 4; kb++) { sv[kb] = __expf(sv[kb] - mn); sum += sv[kb]; }
            #pragma unroll
            for (int d = 1; d < 16; d <<= 1) sum += __shfl_xor(sum, d);
            l[r] = l[r] * al + sum;
            m[r] = mn;
            #pragma unroll
            for (int vb = 0; vb < 4; vb++) acc_o[vb][r] *= al;
            int prow = lg*4 + r;
            int psw = (prow & 7) << 4;
            #pragma unroll
            for (int kb = 0; kb < 4; kb++)
                *(__hip_bfloat16*)(PsB + prow*128 + (((kb*16 + li)*2) ^ psw)) = __float2bfloat16(sv[kb]);
        }

        asm volatile("s_waitcnt lgkmcnt(0)" ::: "memory");
        __builtin_amdgcn_sched_barrier(0);

        bf16x8 pa[2];
        {
            int psw = (li & 7) << 4;
            pa[0] = *(const bf16x8*)(PsB + li*128 + (((lg*8)*2) ^ psw));
            pa[1] = *(const bf16x8*)(PsB + li*128 + (((32 + lg*8)*2) ^ psw));
        }
        #pragma unroll
        for (int vb = 0; vb < 4; vb++) {
            int dim = vb*16 + li;
            int vsw = (dim & 7) << 4;
            bf16x8 vf0 = *(const bf16x8*)(VtB + dim*128 + (((lg*8)*2) ^ vsw));
            bf16x8 vf1 = *(const bf16x8*)(VtB + dim*128 + (((32 + lg*8)*2) ^ vsw));
            acc_o[vb] = __builtin_amdgcn_mfma_f32_16x16x32_bf16(pa[0], vf0, acc_o[vb], 0, 0, 0);
            acc_o[vb] = __builtin_amdgcn_mfma_f32_16x16x32_bf16(pa[1], vf1, acc_o[vb], 0, 0, 0);
        }
        __syncthreads();
    }

    #pragma unroll
    for (int r = 0; r < 4; r++) {
        float inv = 1.0f / l[r];
        int row = qt*64 + w*16 + lg*4 + r;
        #pragma unroll
        for (int vb = 0; vb < 4; vb++)
            ao[(size_t)row*DIM + h*HD + vb*16 + li] = __float2bfloat16(acc_o[vb][r] * inv);
    }
}

extern "C" void kernel_launch(void* const* d_in, const int* in_sizes, int n_in,
                              void* d_out, int out_size, void* d_ws, size_t ws_size,
                              hipStream_t stream) {
    const float* emb   = (const float*)d_in[0];
    const float* normw = (const float*)d_in[1];
    const float* Wq    = (const float*)d_in[2];
    const float* Wk    = (const float*)d_in[3];
    const float* Wv    = (const float*)d_in[4];
    const float* Wo    = (const float*)d_in[5];
    const int*   gidx  = (const int*)d_in[7];
    const int*   sids  = (const int*)d_in[8];
    float* out = (float*)d_out;

    const size_t M4 = (size_t)NTOK * DIM;       // 4M elems
    const size_t M1 = (size_t)DIM * DIM;        // 1M elems
    __hip_bfloat16* xnb = (__hip_bfloat16*)d_ws;            // 4M
    __hip_bfloat16* wqb = xnb + M4;                          // 1M x4
    __hip_bfloat16* wkb = wqb + M1;
    __hip_bfloat16* wvb = wkb + M1;
    __hip_bfloat16* wob = wvb + M1;
    __hip_bfloat16* qb  = wob + M1;                          // 4M x3
    __hip_bfloat16* kb  = qb + M4;
    __hip_bfloat16* vb  = kb + M4;
    __hip_bfloat16* aob = vb + M4;                           // 4M
    float* sint = (float*)(aob + M4);                        // [4096][32]
    float* cost = sint + (size_t)NTOK * 32;
    int*   kvend = (int*)(cost + (size_t)NTOK * 32);

    hipLaunchKernelGGL(k_rmsnorm, dim3(NTOK), dim3(256), 0, stream, emb, normw, xnb);
    hipLaunchKernelGGL(k_w2bf, dim3(M1 / 1024, 4), dim3(256), 0, stream,
                       Wq, Wk, Wv, Wo, wqb, wkb, wvb, wob);
    hipLaunchKernelGGL(k_prep, dim3((NTOK + 255) / 256), dim3(256), 0, stream,
                       sids, gidx, kvend, sint, cost);
    hipLaunchKernelGGL(k_qkv, dim3(NTOK / 128, DIM / 128, 3), dim3(256), 0, stream,
                       xnb, wqb, wkb, wvb, sint, cost, qb, kb, vb);
    hipLaunchKernelGGL(k_attn, dim3(NTOK / 64, HEADS), dim3(256), 0, stream,
                       qb, kb, vb, kvend, aob);
    hipLaunchKernelGGL(k_wo, dim3(NTOK / 128, DIM / 128), dim3(256), 0, stream,
                       aob, wob, out);
}

// Round 5
// 304.897 us; speedup vs baseline: 7.6072x; 1.1647x over previous
//
#include <hip/hip_runtime.h>
#include <hip/hip_bf16.h>
#include <math.h>

#define NTOK 4096
#define DIM  1024
#define HEADS 16
#define HD   64

typedef __attribute__((ext_vector_type(8))) short bf16x8;
typedef __attribute__((ext_vector_type(4))) float f32x4;

// ---------------- RMSNorm: one block per row, bf16 out ----------------
__global__ __launch_bounds__(256) void k_rmsnorm(const float* __restrict__ emb,
                                                 const float* __restrict__ w,
                                                 __hip_bfloat16* __restrict__ xn) {
    int row = blockIdx.x;
    int t = threadIdx.x;
    const float4* e4 = (const float4*)(emb + (size_t)row * DIM);
    float4 x = e4[t];
    float ss = x.x*x.x + x.y*x.y + x.z*x.z + x.w*x.w;
    #pragma unroll
    for (int off = 32; off > 0; off >>= 1) ss += __shfl_down(ss, off);
    __shared__ float red[4];
    int lane = t & 63, wid = t >> 6;
    if (lane == 0) red[wid] = ss;
    __syncthreads();
    float tot = red[0] + red[1] + red[2] + red[3];
    float scale = rsqrtf(tot * (1.0f / (float)DIM) + 1e-6f);
    float4 wv = ((const float4*)w)[t];
    union { __hip_bfloat16 h[4]; uint2 u; } pk;
    pk.h[0] = __float2bfloat16(x.x * scale * wv.x);
    pk.h[1] = __float2bfloat16(x.y * scale * wv.y);
    pk.h[2] = __float2bfloat16(x.z * scale * wv.z);
    pk.h[3] = __float2bfloat16(x.w * scale * wv.w);
    *(uint2*)(xn + (size_t)row * DIM + t * 4) = pk.u;
}

// ---------------- weight f32 -> bf16 ----------------
__global__ __launch_bounds__(256) void k_w2bf(const float* __restrict__ s0, const float* __restrict__ s1,
                                              const float* __restrict__ s2, const float* __restrict__ s3,
                                              __hip_bfloat16* __restrict__ d0, __hip_bfloat16* __restrict__ d1,
                                              __hip_bfloat16* __restrict__ d2, __hip_bfloat16* __restrict__ d3) {
    int z = blockIdx.y;
    const float* s = (z == 0) ? s0 : (z == 1) ? s1 : (z == 2) ? s2 : s3;
    __hip_bfloat16* d = (z == 0) ? d0 : (z == 1) ? d1 : (z == 2) ? d2 : d3;
    size_t i = ((size_t)blockIdx.x * 256 + threadIdx.x) * 4;
    float4 v = *(const float4*)(s + i);
    union { __hip_bfloat16 h[4]; uint2 u; } pk;
    pk.h[0] = __float2bfloat16(v.x);
    pk.h[1] = __float2bfloat16(v.y);
    pk.h[2] = __float2bfloat16(v.z);
    pk.h[3] = __float2bfloat16(v.w);
    *(uint2*)(d + i) = pk.u;
}

// ---------------- prep: seq_end (mask bound) + RoPE tables ----------------
__global__ void k_prep(const int* __restrict__ seq_ids, const int* __restrict__ gidx,
                       int* __restrict__ kv_end, float* __restrict__ sin_t,
                       float* __restrict__ cos_t) {
    int n = blockIdx.x * blockDim.x + threadIdx.x;
    if (n >= NTOK) return;
    int id = seq_ids[n];
    int lo = n + 1, hi = NTOK;
    while (lo < hi) {
        int mid = (lo + hi) >> 1;
        if (seq_ids[mid] == id) lo = mid + 1; else hi = mid;
    }
    kv_end[n] = lo;  // union of causal and same-block == j < seq_end[n]
    double pos = (double)gidx[n];
    const double lt = 13.122363377404328;  // log(500000)
    for (int f = 0; f < 32; f++) {
        double ang = pos * exp(-(double)f * (1.0 / 32.0) * lt);
        sin_t[n * 32 + f] = (float)sin(ang);
        cos_t[n * 32 + f] = (float)cos(ang);
    }
}

// ---------------- shared MFMA GEMM core (128x128 tile, BK=32) ----------------
__device__ __forceinline__ void gemm_core(const __hip_bfloat16* __restrict__ A,
                                          const __hip_bfloat16* __restrict__ B,
                                          short* As, short* Bs,
                                          int bm, int bn, f32x4 (&acc)[4][4], int t) {
    int w = t >> 6, l = t & 63;
    int wm = w >> 1, wn = w & 1;
    int li = l & 15, lg = l >> 4;
    int lr = l >> 2, lc = l & 3;
    for (int kt = 0; kt < DIM; kt += 32) {
        #pragma unroll
        for (int i = 0; i < 2; i++) {
            int r = w * 32 + i * 16 + lr;
            int c = lc ^ ((r >> 1) & 3);
            const __hip_bfloat16* ga = A + (size_t)(bm * 128 + r) * DIM + kt + c * 8;
            __builtin_amdgcn_global_load_lds(
                (const __attribute__((address_space(1))) unsigned int*)ga,
                (__attribute__((address_space(3))) unsigned int*)(As + (w * 32 + i * 16) * 32),
                16, 0, 0);
            const __hip_bfloat16* gb = B + (size_t)(bn * 128 + r) * DIM + kt + c * 8;
            __builtin_amdgcn_global_load_lds(
                (const __attribute__((address_space(1))) unsigned int*)gb,
                (__attribute__((address_space(3))) unsigned int*)(Bs + (w * 32 + i * 16) * 32),
                16, 0, 0);
        }
        __syncthreads();
        bf16x8 af[4], bfr[4];
        #pragma unroll
        for (int mb = 0; mb < 4; mb++) {
            int r = wm * 64 + mb * 16 + li;
            af[mb] = *(const bf16x8*)((const char*)As + r * 64 + ((lg ^ ((r >> 1) & 3)) << 4));
        }
        #pragma unroll
        for (int nb = 0; nb < 4; nb++) {
            int r = wn * 64 + nb * 16 + li;
            bfr[nb] = *(const bf16x8*)((const char*)Bs + r * 64 + ((lg ^ ((r >> 1) & 3)) << 4));
        }
        #pragma unroll
        for (int mb = 0; mb < 4; mb++)
            #pragma unroll
            for (int nb = 0; nb < 4; nb++)
                acc[mb][nb] = __builtin_amdgcn_mfma_f32_16x16x32_bf16(af[mb], bfr[nb], acc[mb][nb], 0, 0, 0);
        __syncthreads();
    }
}

// ---------------- QKV projection + clip + RoPE (all MFMA) ----------------
__global__ __launch_bounds__(256) void k_qkv(const __hip_bfloat16* __restrict__ xn,
                                             const __hip_bfloat16* __restrict__ wq,
                                             const __hip_bfloat16* __restrict__ wk,
                                             const __hip_bfloat16* __restrict__ wv,
                                             const float* __restrict__ sin_t,
                                             const float* __restrict__ cos_t,
                                             __hip_bfloat16* __restrict__ qo,
                                             __hip_bfloat16* __restrict__ ko,
                                             __hip_bfloat16* __restrict__ vo) {
    __shared__ alignas(16) short As[128 * 32];
    __shared__ alignas(16) short Bs[128 * 32];
    int bm = blockIdx.x, bn = blockIdx.y, z = blockIdx.z;
    const __hip_bfloat16* W = (z == 0) ? wq : (z == 1) ? wk : wv;
    __hip_bfloat16* out = (z == 0) ? qo : (z == 1) ? ko : vo;
    int t = threadIdx.x;
    f32x4 acc[4][4] = {};
    gemm_core(xn, W, As, Bs, bm, bn, acc, t);

    int w = t >> 6, l = t & 63;
    int wm = w >> 1, wn = w & 1;
    int li = l & 15, lg = l >> 4;
    #pragma unroll
    for (int mb = 0; mb < 4; mb++)
        #pragma unroll
        for (int nb = 0; nb < 4; nb++)
            #pragma unroll
            for (int r = 0; r < 4; r++)
                acc[mb][nb][r] = fminf(fmaxf(acc[mb][nb][r], -8.0f), 8.0f);

    int h = bn * 2 + wn;   // wave owns one full head (64 cols)
    if (z < 2) {
        // RoPE in-register: partner d+-32 = fragment nb^2, same lane.
        #pragma unroll
        for (int mb = 0; mb < 4; mb++) {
            #pragma unroll
            for (int r = 0; r < 4; r++) {
                int n = bm * 128 + wm * 64 + mb * 16 + lg * 4 + r;
                float s0 = sin_t[n * 32 + li],      c0 = cos_t[n * 32 + li];
                float s1 = sin_t[n * 32 + 16 + li], c1 = cos_t[n * 32 + 16 + li];
                float v0 = acc[mb][0][r], v1 = acc[mb][1][r];
                float v2 = acc[mb][2][r], v3 = acc[mb][3][r];
                __hip_bfloat16* op = out + ((size_t)h * NTOK + n) * HD + li;
                op[0]  = __float2bfloat16(v0 * c0 - v2 * s0);
                op[16] = __float2bfloat16(v1 * c1 - v3 * s1);
                op[32] = __float2bfloat16(v2 * c0 + v0 * s0);
                op[48] = __float2bfloat16(v3 * c1 + v1 * s1);
            }
        }
    } else {
        #pragma unroll
        for (int mb = 0; mb < 4; mb++) {
            #pragma unroll
            for (int r = 0; r < 4; r++) {
                int n = bm * 128 + wm * 64 + mb * 16 + lg * 4 + r;
                __hip_bfloat16* op = out + ((size_t)h * NTOK + n) * HD + li;
                op[0]  = __float2bfloat16(acc[mb][0][r]);
                op[16] = __float2bfloat16(acc[mb][1][r]);
                op[32] = __float2bfloat16(acc[mb][2][r]);
                op[48] = __float2bfloat16(acc[mb][3][r]);
            }
        }
    }
}

// ---------------- output projection (MFMA), f32 out ----------------
__global__ __launch_bounds__(256) void k_wo(const __hip_bfloat16* __restrict__ ao,
                                            const __hip_bfloat16* __restrict__ wo,
                                            float* __restrict__ out) {
    __shared__ alignas(16) short As[128 * 32];
    __shared__ alignas(16) short Bs[128 * 32];
    int bm = blockIdx.x, bn = blockIdx.y;
    int t = threadIdx.x;
    f32x4 acc[4][4] = {};
    gemm_core(ao, wo, As, Bs, bm, bn, acc, t);

    int w = t >> 6, l = t & 63;
    int wm = w >> 1, wn = w & 1;
    int li = l & 15, lg = l >> 4;
    #pragma unroll
    for (int mb = 0; mb < 4; mb++) {
        #pragma unroll
        for (int r = 0; r < 4; r++) {
            int n = bm * 128 + wm * 64 + mb * 16 + lg * 4 + r;
            float* op = out + (size_t)n * DIM + bn * 128 + wn * 64 + li;
            op[0]  = acc[mb][0][r];
            op[16] = acc[mb][1][r];
            op[32] = acc[mb][2][r];
            op[48] = acc[mb][3][r];
        }
    }
}

// ---------------- flash attention, swapped-QK^T bf16 MFMA ----------------
// 4 waves; wave w owns q rows w*16..w*16+15 of the 64-row tile.
// S^T = mfma(K,Q): lane (li,lg) holds S[key=kb*16+lg*4+r][q=li] -> softmax
// nearly in-lane (2 shfl per reduce). P redistributed to PV A-frags by shfl.
__global__ __launch_bounds__(256) void k_attn(const __hip_bfloat16* __restrict__ qg,
                                              const __hip_bfloat16* __restrict__ kg,
                                              const __hip_bfloat16* __restrict__ vg,
                                              const int* __restrict__ kv_end,
                                              __hip_bfloat16* __restrict__ ao) {
    int qt = (int)gridDim.x - 1 - (int)blockIdx.x;   // long blocks first
    int h = blockIdx.y;
    int t = threadIdx.x;
    int w = t >> 6, lane = t & 63;
    int lg = lane >> 4, li = lane & 15;

    __shared__ short Ks[64 * 64];   // [key][hd]   swz: byte ^ (key&7)<<4
    __shared__ short Vt[64 * 64];   // [dim][key]  swz: byte ^ ((d&7)<<4 ^ ((d>>4)&3)<<5)
    char* KsB = (char*)Ks;
    char* VtB = (char*)Vt;

    const __hip_bfloat16* qh = qg + ((size_t)h * NTOK + (size_t)qt * 64) * HD;
    int qrow = w * 16 + li;
    bf16x8 qa[2];
    qa[0] = *(const bf16x8*)(qh + qrow * HD + lg * 8);
    qa[1] = *(const bf16x8*)(qh + qrow * HD + lg * 8 + 32);

    int ke = kv_end[qt * 64 + w * 16 + li];       // bound for q = li (lane-local)
    int kmax = kv_end[qt * 64 + 63];              // ids sorted -> monotone

    float m = -1e30f, l = 0.f;
    f32x4 acc_o[4] = {};

    int skey = t >> 2;            // staging: key row 0..63
    int sc0 = (t & 3) * 16;       // staging: 16-elem chunk
    const float SC = 0.18033688011112042f;        // 0.125 * log2(e)

    // prefetch tile 0
    const __hip_bfloat16* kh = kg + ((size_t)h * NTOK + skey) * HD;
    const __hip_bfloat16* vh = vg + ((size_t)h * NTOK + skey) * HD;
    bf16x8 kr0 = *(const bf16x8*)(kh + sc0);
    bf16x8 kr1 = *(const bf16x8*)(kh + sc0 + 8);
    bf16x8 vr0 = *(const bf16x8*)(vh + sc0);
    bf16x8 vr1 = *(const bf16x8*)(vh + sc0 + 8);

    for (int jt = 0; jt < kmax; jt += 64) {
        // ---- stage regs -> LDS ----
        int kswz = (skey & 7) << 4;
        *(bf16x8*)(KsB + skey * 128 + ((sc0 * 2) ^ kswz)) = kr0;
        *(bf16x8*)(KsB + skey * 128 + ((sc0 * 2 + 16) ^ kswz)) = kr1;
        int vsega = (((sc0 >> 4) & 3) << 5);
        #pragma unroll
        for (int j = 0; j < 8; j++) {
            int r0 = sc0 + j, r1 = sc0 + 8 + j;
            *(short*)(VtB + r0 * 128 + ((skey * 2) ^ (((r0 & 7) << 4) ^ vsega))) = vr0[j];
            *(short*)(VtB + r1 * 128 + ((skey * 2) ^ (((r1 & 7) << 4) ^ vsega))) = vr1[j];
        }
        __syncthreads();

        // ---- prefetch next tile (latency hides under compute) ----
        if (jt + 64 < kmax) {
            const __hip_bfloat16* kh2 = kg + ((size_t)h * NTOK + jt + 64 + skey) * HD;
            const __hip_bfloat16* vh2 = vg + ((size_t)h * NTOK + jt + 64 + skey) * HD;
            kr0 = *(const bf16x8*)(kh2 + sc0);
            kr1 = *(const bf16x8*)(kh2 + sc0 + 8);
            vr0 = *(const bf16x8*)(vh2 + sc0);
            vr1 = *(const bf16x8*)(vh2 + sc0 + 8);
        }

        // ---- S^T = K Q^T : D[key][q], col q = li, row key = kb*16+lg*4+r ----
        f32x4 sacc[4] = {};
        #pragma unroll
        for (int kb = 0; kb < 4; kb++) {
            int key = kb * 16 + li;
            int ksw = (key & 7) << 4;
            bf16x8 kf0 = *(const bf16x8*)(KsB + key * 128 + ((lg * 16) ^ ksw));
            bf16x8 kf1 = *(const bf16x8*)(KsB + key * 128 + ((64 + lg * 16) ^ ksw));
            sacc[kb] = __builtin_amdgcn_mfma_f32_16x16x32_bf16(kf0, qa[0], sacc[kb], 0, 0, 0);
            sacc[kb] = __builtin_amdgcn_mfma_f32_16x16x32_bf16(kf1, qa[1], sacc[kb], 0, 0, 0);
        }

        // ---- online softmax in log2 domain (row q = li, 16 vals in-lane) ----
        float p[4][4];
        #pragma unroll
        for (int kb = 0; kb < 4; kb++)
            #pragma unroll
            for (int r = 0; r < 4; r++) {
                int j = jt + kb * 16 + lg * 4 + r;
                p[kb][r] = (j < ke) ? sacc[kb][r] * SC : -1e30f;
            }
        float mx = -1e30f;
        #pragma unroll
        for (int kb = 0; kb < 4; kb++)
            #pragma unroll
            for (int r = 0; r < 4; r++) mx = fmaxf(mx, p[kb][r]);
        mx = fmaxf(mx, __shfl_xor(mx, 16));
        mx = fmaxf(mx, __shfl_xor(mx, 32));
        float mn = fmaxf(m, mx);
        float al = exp2f(m - mn);
        float sum = 0.f;
        #pragma unroll
        for (int kb = 0; kb < 4; kb++)
            #pragma unroll
            for (int r = 0; r < 4; r++) { p[kb][r] = exp2f(p[kb][r] - mn); sum += p[kb][r]; }
        sum += __shfl_xor(sum, 16);
        sum += __shfl_xor(sum, 32);
        l = l * al + sum;
        m = mn;

        // rescale O (al lives at q=li; O rows are q=lg*4+r)
        float alr[4];
        #pragma unroll
        for (int r = 0; r < 4; r++) alr[r] = __shfl(al, lg * 4 + r);
        #pragma unroll
        for (int vb = 0; vb < 4; vb++)
            #pragma unroll
            for (int r = 0; r < 4; r++) acc_o[vb][r] *= alr[r];

        // ---- pack P to bf16 pairs, redistribute to PV A-frags via shfl ----
        uint pu[4][2];
        #pragma unroll
        for (int kb = 0; kb < 4; kb++)
            #pragma unroll
            for (int w2 = 0; w2 < 2; w2++) {
                union { __hip_bfloat16 b[2]; uint u; } cv;
                cv.b[0] = __float2bfloat16(p[kb][2 * w2]);
                cv.b[1] = __float2bfloat16(p[kb][2 * w2 + 1]);
                pu[kb][w2] = cv.u;
            }
        union { uint u[4]; bf16x8 v; } pa0, pa1;
        #pragma unroll
        for (int ww = 0; ww < 4; ww++) {
            int src = ((lg & 1) * 2 + (ww >> 1)) * 16 + li;
            uint a0 = (uint)__shfl((int)pu[0][ww & 1], src);
            uint a1 = (uint)__shfl((int)pu[1][ww & 1], src);
            uint b0 = (uint)__shfl((int)pu[2][ww & 1], src);
            uint b1 = (uint)__shfl((int)pu[3][ww & 1], src);
            pa0.u[ww] = (lg >> 1) ? a1 : a0;
            pa1.u[ww] = (lg >> 1) ? b1 : b0;
        }

        // ---- O += P V : D[q][d], col d = li, row q = lg*4+r ----
        #pragma unroll
        for (int vb = 0; vb < 4; vb++) {
            int d = vb * 16 + li;
            int vsw = ((d & 7) << 4) ^ ((vb & 3) << 5);
            bf16x8 vf0 = *(const bf16x8*)(VtB + d * 128 + ((lg * 16) ^ vsw));
            bf16x8 vf1 = *(const bf16x8*)(VtB + d * 128 + ((64 + lg * 16) ^ vsw));
            acc_o[vb] = __builtin_amdgcn_mfma_f32_16x16x32_bf16(pa0.v, vf0, acc_o[vb], 0, 0, 0);
            acc_o[vb] = __builtin_amdgcn_mfma_f32_16x16x32_bf16(pa1.v, vf1, acc_o[vb], 0, 0, 0);
        }
        __syncthreads();
    }

    float lr[4];
    #pragma unroll
    for (int r = 0; r < 4; r++) lr[r] = 1.0f / __shfl(l, lg * 4 + r);
    #pragma unroll
    for (int r = 0; r < 4; r++) {
        int row = qt * 64 + w * 16 + lg * 4 + r;
        #pragma unroll
        for (int vb = 0; vb < 4; vb++)
            ao[(size_t)row * DIM + h * HD + vb * 16 + li] = __float2bfloat16(acc_o[vb][r] * lr[r]);
    }
}

extern "C" void kernel_launch(void* const* d_in, const int* in_sizes, int n_in,
                              void* d_out, int out_size, void* d_ws, size_t ws_size,
                              hipStream_t stream) {
    const float* emb   = (const float*)d_in[0];
    const float* normw = (const float*)d_in[1];
    const float* Wq    = (const float*)d_in[2];
    const float* Wk    = (const float*)d_in[3];
    const float* Wv    = (const float*)d_in[4];
    const float* Wo    = (const float*)d_in[5];
    const int*   gidx  = (const int*)d_in[7];
    const int*   sids  = (const int*)d_in[8];
    float* out = (float*)d_out;

    const size_t M4 = (size_t)NTOK * DIM;
    const size_t M1 = (size_t)DIM * DIM;
    __hip_bfloat16* xnb = (__hip_bfloat16*)d_ws;             // 4M
    __hip_bfloat16* wqb = xnb + M4;                          // 1M x4
    __hip_bfloat16* wkb = wqb + M1;
    __hip_bfloat16* wvb = wkb + M1;
    __hip_bfloat16* wob = wvb + M1;
    __hip_bfloat16* qb  = wob + M1;                          // 4M x3
    __hip_bfloat16* kb  = qb + M4;
    __hip_bfloat16* vb  = kb + M4;
    __hip_bfloat16* aob = vb + M4;                           // 4M
    float* sint = (float*)(aob + M4);                        // [4096][32]
    float* cost = sint + (size_t)NTOK * 32;
    int*   kvend = (int*)(cost + (size_t)NTOK * 32);

    hipLaunchKernelGGL(k_rmsnorm, dim3(NTOK), dim3(256), 0, stream, emb, normw, xnb);
    hipLaunchKernelGGL(k_w2bf, dim3(M1 / 1024, 4), dim3(256), 0, stream,
                       Wq, Wk, Wv, Wo, wqb, wkb, wvb, wob);
    hipLaunchKernelGGL(k_prep, dim3((NTOK + 255) / 256), dim3(256), 0, stream,
                       sids, gidx, kvend, sint, cost);
    hipLaunchKernelGGL(k_qkv, dim3(NTOK / 128, DIM / 128, 3), dim3(256), 0, stream,
                       xnb, wqb, wkb, wvb, sint, cost, qb, kb, vb);
    hipLaunchKernelGGL(k_attn, dim3(NTOK / 64, HEADS), dim3(256), 0, stream,
                       qb, kb, vb, kvend, aob);
    hipLaunchKernelGGL(k_wo, dim3(NTOK / 128, DIM / 128), dim3(256), 0, stream,
                       aob, wob, out);
}

// Round 6
// 284.169 us; speedup vs baseline: 8.1621x; 1.0729x over previous
//
#include <hip/hip_runtime.h>
#include <hip/hip_bf16.h>
#include <math.h>

#define NTOK 4096
#define DIM  1024
#define HEADS 16
#define HD   64
#define CHUNK 1024
#define MAXCH (NTOK / CHUNK)

typedef __attribute__((ext_vector_type(8))) short bf16x8;
typedef __attribute__((ext_vector_type(4))) float f32x4;

// ---------------- RMSNorm: one block per row, bf16 out ----------------
__global__ __launch_bounds__(256) void k_rmsnorm(const float* __restrict__ emb,
                                                 const float* __restrict__ w,
                                                 __hip_bfloat16* __restrict__ xn) {
    int row = blockIdx.x;
    int t = threadIdx.x;
    const float4* e4 = (const float4*)(emb + (size_t)row * DIM);
    float4 x = e4[t];
    float ss = x.x*x.x + x.y*x.y + x.z*x.z + x.w*x.w;
    #pragma unroll
    for (int off = 32; off > 0; off >>= 1) ss += __shfl_down(ss, off);
    __shared__ float red[4];
    int lane = t & 63, wid = t >> 6;
    if (lane == 0) red[wid] = ss;
    __syncthreads();
    float tot = red[0] + red[1] + red[2] + red[3];
    float scale = rsqrtf(tot * (1.0f / (float)DIM) + 1e-6f);
    float4 wv = ((const float4*)w)[t];
    union { __hip_bfloat16 h[4]; uint2 u; } pk;
    pk.h[0] = __float2bfloat16(x.x * scale * wv.x);
    pk.h[1] = __float2bfloat16(x.y * scale * wv.y);
    pk.h[2] = __float2bfloat16(x.z * scale * wv.z);
    pk.h[3] = __float2bfloat16(x.w * scale * wv.w);
    *(uint2*)(xn + (size_t)row * DIM + t * 4) = pk.u;
}

// ---------------- weight f32 -> bf16 ----------------
__global__ __launch_bounds__(256) void k_w2bf(const float* __restrict__ s0, const float* __restrict__ s1,
                                              const float* __restrict__ s2, const float* __restrict__ s3,
                                              __hip_bfloat16* __restrict__ d0, __hip_bfloat16* __restrict__ d1,
                                              __hip_bfloat16* __restrict__ d2, __hip_bfloat16* __restrict__ d3) {
    int z = blockIdx.y;
    const float* s = (z == 0) ? s0 : (z == 1) ? s1 : (z == 2) ? s2 : s3;
    __hip_bfloat16* d = (z == 0) ? d0 : (z == 1) ? d1 : (z == 2) ? d2 : d3;
    size_t i = ((size_t)blockIdx.x * 256 + threadIdx.x) * 4;
    float4 v = *(const float4*)(s + i);
    union { __hip_bfloat16 h[4]; uint2 u; } pk;
    pk.h[0] = __float2bfloat16(v.x);
    pk.h[1] = __float2bfloat16(v.y);
    pk.h[2] = __float2bfloat16(v.z);
    pk.h[3] = __float2bfloat16(v.w);
    *(uint2*)(d + i) = pk.u;
}

// ---------------- prep: seq_end (mask bound) + RoPE tables ----------------
__global__ void k_prep(const int* __restrict__ seq_ids, const int* __restrict__ gidx,
                       int* __restrict__ kv_end, float* __restrict__ sin_t,
                       float* __restrict__ cos_t) {
    int n = blockIdx.x * blockDim.x + threadIdx.x;
    if (n >= NTOK) return;
    int id = seq_ids[n];
    int lo = n + 1, hi = NTOK;
    while (lo < hi) {
        int mid = (lo + hi) >> 1;
        if (seq_ids[mid] == id) lo = mid + 1; else hi = mid;
    }
    kv_end[n] = lo;  // union of causal and same-block == j < seq_end[n]
    double pos = (double)gidx[n];
    const double lt = 13.122363377404328;  // log(500000)
    for (int f = 0; f < 32; f++) {
        double ang = pos * exp(-(double)f * (1.0 / 32.0) * lt);
        sin_t[n * 32 + f] = (float)sin(ang);
        cos_t[n * 32 + f] = (float)cos(ang);
    }
}

// ---------------- shared MFMA GEMM core (128x128 tile, BK=32) ----------------
__device__ __forceinline__ void gemm_core(const __hip_bfloat16* __restrict__ A,
                                          const __hip_bfloat16* __restrict__ B,
                                          short* As, short* Bs,
                                          int bm, int bn, f32x4 (&acc)[4][4], int t) {
    int w = t >> 6, l = t & 63;
    int wm = w >> 1, wn = w & 1;
    int li = l & 15, lg = l >> 4;
    int lr = l >> 2, lc = l & 3;
    for (int kt = 0; kt < DIM; kt += 32) {
        #pragma unroll
        for (int i = 0; i < 2; i++) {
            int r = w * 32 + i * 16 + lr;
            int c = lc ^ ((r >> 1) & 3);
            const __hip_bfloat16* ga = A + (size_t)(bm * 128 + r) * DIM + kt + c * 8;
            __builtin_amdgcn_global_load_lds(
                (const __attribute__((address_space(1))) unsigned int*)ga,
                (__attribute__((address_space(3))) unsigned int*)(As + (w * 32 + i * 16) * 32),
                16, 0, 0);
            const __hip_bfloat16* gb = B + (size_t)(bn * 128 + r) * DIM + kt + c * 8;
            __builtin_amdgcn_global_load_lds(
                (const __attribute__((address_space(1))) unsigned int*)gb,
                (__attribute__((address_space(3))) unsigned int*)(Bs + (w * 32 + i * 16) * 32),
                16, 0, 0);
        }
        __syncthreads();
        bf16x8 af[4], bfr[4];
        #pragma unroll
        for (int mb = 0; mb < 4; mb++) {
            int r = wm * 64 + mb * 16 + li;
            af[mb] = *(const bf16x8*)((const char*)As + r * 64 + ((lg ^ ((r >> 1) & 3)) << 4));
        }
        #pragma unroll
        for (int nb = 0; nb < 4; nb++) {
            int r = wn * 64 + nb * 16 + li;
            bfr[nb] = *(const bf16x8*)((const char*)Bs + r * 64 + ((lg ^ ((r >> 1) & 3)) << 4));
        }
        #pragma unroll
        for (int mb = 0; mb < 4; mb++)
            #pragma unroll
            for (int nb = 0; nb < 4; nb++)
                acc[mb][nb] = __builtin_amdgcn_mfma_f32_16x16x32_bf16(af[mb], bfr[nb], acc[mb][nb], 0, 0, 0);
        __syncthreads();
    }
}

// ---------------- QKV projection + clip + RoPE (all MFMA) ----------------
__global__ __launch_bounds__(256) void k_qkv(const __hip_bfloat16* __restrict__ xn,
                                             const __hip_bfloat16* __restrict__ wq,
                                             const __hip_bfloat16* __restrict__ wk,
                                             const __hip_bfloat16* __restrict__ wv,
                                             const float* __restrict__ sin_t,
                                             const float* __restrict__ cos_t,
                                             __hip_bfloat16* __restrict__ qo,
                                             __hip_bfloat16* __restrict__ ko,
                                             __hip_bfloat16* __restrict__ vo) {
    __shared__ alignas(16) short As[128 * 32];
    __shared__ alignas(16) short Bs[128 * 32];
    int bm = blockIdx.x, bn = blockIdx.y, z = blockIdx.z;
    const __hip_bfloat16* W = (z == 0) ? wq : (z == 1) ? wk : wv;
    __hip_bfloat16* out = (z == 0) ? qo : (z == 1) ? ko : vo;
    int t = threadIdx.x;
    f32x4 acc[4][4] = {};
    gemm_core(xn, W, As, Bs, bm, bn, acc, t);

    int w = t >> 6, l = t & 63;
    int wm = w >> 1, wn = w & 1;
    int li = l & 15, lg = l >> 4;
    #pragma unroll
    for (int mb = 0; mb < 4; mb++)
        #pragma unroll
        for (int nb = 0; nb < 4; nb++)
            #pragma unroll
            for (int r = 0; r < 4; r++)
                acc[mb][nb][r] = fminf(fmaxf(acc[mb][nb][r], -8.0f), 8.0f);

    int h = bn * 2 + wn;   // wave owns one full head (64 cols)
    if (z < 2) {
        // RoPE in-register: partner d+-32 = fragment nb^2, same lane.
        #pragma unroll
        for (int mb = 0; mb < 4; mb++) {
            #pragma unroll
            for (int r = 0; r < 4; r++) {
                int n = bm * 128 + wm * 64 + mb * 16 + lg * 4 + r;
                float s0 = sin_t[n * 32 + li],      c0 = cos_t[n * 32 + li];
                float s1 = sin_t[n * 32 + 16 + li], c1 = cos_t[n * 32 + 16 + li];
                float v0 = acc[mb][0][r], v1 = acc[mb][1][r];
                float v2 = acc[mb][2][r], v3 = acc[mb][3][r];
                __hip_bfloat16* op = out + ((size_t)h * NTOK + n) * HD + li;
                op[0]  = __float2bfloat16(v0 * c0 - v2 * s0);
                op[16] = __float2bfloat16(v1 * c1 - v3 * s1);
                op[32] = __float2bfloat16(v2 * c0 + v0 * s0);
                op[48] = __float2bfloat16(v3 * c1 + v1 * s1);
            }
        }
    } else {
        #pragma unroll
        for (int mb = 0; mb < 4; mb++) {
            #pragma unroll
            for (int r = 0; r < 4; r++) {
                int n = bm * 128 + wm * 64 + mb * 16 + lg * 4 + r;
                __hip_bfloat16* op = out + ((size_t)h * NTOK + n) * HD + li;
                op[0]  = __float2bfloat16(acc[mb][0][r]);
                op[16] = __float2bfloat16(acc[mb][1][r]);
                op[32] = __float2bfloat16(acc[mb][2][r]);
                op[48] = __float2bfloat16(acc[mb][3][r]);
            }
        }
    }
}

// ---------------- output projection (MFMA), f32 out ----------------
__global__ __launch_bounds__(256) void k_wo(const __hip_bfloat16* __restrict__ ao,
                                            const __hip_bfloat16* __restrict__ wo,
                                            float* __restrict__ out) {
    __shared__ alignas(16) short As[128 * 32];
    __shared__ alignas(16) short Bs[128 * 32];
    int bm = blockIdx.x, bn = blockIdx.y;
    int t = threadIdx.x;
    f32x4 acc[4][4] = {};
    gemm_core(ao, wo, As, Bs, bm, bn, acc, t);

    int w = t >> 6, l = t & 63;
    int wm = w >> 1, wn = w & 1;
    int li = l & 15, lg = l >> 4;
    #pragma unroll
    for (int mb = 0; mb < 4; mb++) {
        #pragma unroll
        for (int r = 0; r < 4; r++) {
            int n = bm * 128 + wm * 64 + mb * 16 + lg * 4 + r;
            float* op = out + (size_t)n * DIM + bn * 128 + wn * 64 + li;
            op[0]  = acc[mb][0][r];
            op[16] = acc[mb][1][r];
            op[32] = acc[mb][2][r];
            op[48] = acc[mb][3][r];
        }
    }
}

// ---------------- split-K flash attention, swapped-QK^T bf16 MFMA ----------------
// grid (64, HEADS, MAXCH); block computes partial over keys [c*CHUNK, jend).
// S^T = mfma(K,Q): lane (li,lg) holds S[key=kb*16+lg*4+r][q=li]; softmax 2-shfl.
__global__ __launch_bounds__(256) void k_attn(const __hip_bfloat16* __restrict__ qg,
                                              const __hip_bfloat16* __restrict__ kg,
                                              const __hip_bfloat16* __restrict__ vg,
                                              const int* __restrict__ kv_end,
                                              float* __restrict__ opart,
                                              float* __restrict__ mlpart,
                                              __hip_bfloat16* __restrict__ ao) {
    int qt = (int)gridDim.x - 1 - (int)blockIdx.x;   // long blocks first
    int h = blockIdx.y;
    int c = blockIdx.z;
    int kmaxf = kv_end[qt * 64 + 63];                // ids sorted -> monotone bound
    int jstart = c * CHUNK;
    if (jstart >= kmaxf) return;                     // c==0 always valid
    int jend = min(jstart + CHUNK, kmaxf);
    int nch = (kmaxf + CHUNK - 1) / CHUNK;

    int t = threadIdx.x;
    int w = t >> 6, lane = t & 63;
    int lg = lane >> 4, li = lane & 15;

    __shared__ short Ks[64 * 64];   // [key][hd]   swz: byte ^ (key&7)<<4
    __shared__ short Vt[64 * 64];   // [dim][key]  swz: byte ^ ((d&7)<<4 ^ ((d>>4)&3)<<5)
    char* KsB = (char*)Ks;
    char* VtB = (char*)Vt;

    const __hip_bfloat16* qh = qg + ((size_t)h * NTOK + (size_t)qt * 64) * HD;
    int qrow = w * 16 + li;
    bf16x8 qa[2];
    qa[0] = *(const bf16x8*)(qh + qrow * HD + lg * 8);
    qa[1] = *(const bf16x8*)(qh + qrow * HD + lg * 8 + 32);

    int ke = kv_end[qt * 64 + w * 16 + li];          // bound for q = li (lane-local)
    int wave_kemax = kv_end[qt * 64 + w * 16 + 15];  // wave-level activity bound

    float m = -1e30f, l = 0.f;
    f32x4 acc_o[4] = {};

    int skey = t >> 2;            // staging: key row 0..63
    int sc0 = (t & 3) * 16;       // staging: 16-elem chunk
    const float SC = 0.18033688011112042f;           // 0.125 * log2(e)

    // prefetch first tile
    const __hip_bfloat16* kh = kg + ((size_t)h * NTOK + jstart + skey) * HD;
    const __hip_bfloat16* vh = vg + ((size_t)h * NTOK + jstart + skey) * HD;
    bf16x8 kr0 = *(const bf16x8*)(kh + sc0);
    bf16x8 kr1 = *(const bf16x8*)(kh + sc0 + 8);
    bf16x8 vr0 = *(const bf16x8*)(vh + sc0);
    bf16x8 vr1 = *(const bf16x8*)(vh + sc0 + 8);

    for (int jt = jstart; jt < jend; jt += 64) {
        // ---- stage regs -> LDS ----
        int kswz = (skey & 7) << 4;
        *(bf16x8*)(KsB + skey * 128 + ((sc0 * 2) ^ kswz)) = kr0;
        *(bf16x8*)(KsB + skey * 128 + ((sc0 * 2 + 16) ^ kswz)) = kr1;
        int vsega = (((sc0 >> 4) & 3) << 5);
        #pragma unroll
        for (int j = 0; j < 8; j++) {
            int r0 = sc0 + j, r1 = sc0 + 8 + j;
            *(short*)(VtB + r0 * 128 + ((skey * 2) ^ (((r0 & 7) << 4) ^ vsega))) = vr0[j];
            *(short*)(VtB + r1 * 128 + ((skey * 2) ^ (((r1 & 7) << 4) ^ vsega))) = vr1[j];
        }
        __syncthreads();

        // ---- prefetch next tile (latency hides under compute) ----
        if (jt + 64 < jend) {
            const __hip_bfloat16* kh2 = kg + ((size_t)h * NTOK + jt + 64 + skey) * HD;
            const __hip_bfloat16* vh2 = vg + ((size_t)h * NTOK + jt + 64 + skey) * HD;
            kr0 = *(const bf16x8*)(kh2 + sc0);
            kr1 = *(const bf16x8*)(kh2 + sc0 + 8);
            vr0 = *(const bf16x8*)(vh2 + sc0);
            vr1 = *(const bf16x8*)(vh2 + sc0 + 8);
        }

        if (wave_kemax > jt) {   // wave-uniform: skip fully-masked waves
            // ---- S^T = K Q^T ----
            f32x4 sacc[4] = {};
            __builtin_amdgcn_s_setprio(1);
            #pragma unroll
            for (int kb = 0; kb < 4; kb++) {
                int key = kb * 16 + li;
                int ksw = (key & 7) << 4;
                bf16x8 kf0 = *(const bf16x8*)(KsB + key * 128 + ((lg * 16) ^ ksw));
                bf16x8 kf1 = *(const bf16x8*)(KsB + key * 128 + ((64 + lg * 16) ^ ksw));
                sacc[kb] = __builtin_amdgcn_mfma_f32_16x16x32_bf16(kf0, qa[0], sacc[kb], 0, 0, 0);
                sacc[kb] = __builtin_amdgcn_mfma_f32_16x16x32_bf16(kf1, qa[1], sacc[kb], 0, 0, 0);
            }
            __builtin_amdgcn_s_setprio(0);

            // ---- online softmax in log2 domain (row q = li, 16 vals in-lane) ----
            float p[4][4];
            #pragma unroll
            for (int kb = 0; kb < 4; kb++)
                #pragma unroll
                for (int r = 0; r < 4; r++) {
                    int j = jt + kb * 16 + lg * 4 + r;
                    p[kb][r] = (j < ke) ? sacc[kb][r] * SC : -1e30f;
                }
            float mx = -1e30f;
            #pragma unroll
            for (int kb = 0; kb < 4; kb++)
                #pragma unroll
                for (int r = 0; r < 4; r++) mx = fmaxf(mx, p[kb][r]);
            mx = fmaxf(mx, __shfl_xor(mx, 16));
            mx = fmaxf(mx, __shfl_xor(mx, 32));

            float sum = 0.f;
            if (__all(mx <= m)) {
                // no new max: mn = m, al = 1 -> skip rescale entirely
                #pragma unroll
                for (int kb = 0; kb < 4; kb++)
                    #pragma unroll
                    for (int r = 0; r < 4; r++) { p[kb][r] = exp2f(p[kb][r] - m); sum += p[kb][r]; }
                sum += __shfl_xor(sum, 16);
                sum += __shfl_xor(sum, 32);
                l = l + sum;
            } else {
                float mn = fmaxf(m, mx);
                float al = exp2f(m - mn);
                #pragma unroll
                for (int kb = 0; kb < 4; kb++)
                    #pragma unroll
                    for (int r = 0; r < 4; r++) { p[kb][r] = exp2f(p[kb][r] - mn); sum += p[kb][r]; }
                sum += __shfl_xor(sum, 16);
                sum += __shfl_xor(sum, 32);
                l = l * al + sum;
                m = mn;
                float alr[4];
                #pragma unroll
                for (int r = 0; r < 4; r++) alr[r] = __shfl(al, lg * 4 + r);
                #pragma unroll
                for (int vb = 0; vb < 4; vb++)
                    #pragma unroll
                    for (int r = 0; r < 4; r++) acc_o[vb][r] *= alr[r];
            }

            // ---- pack P to bf16 pairs, redistribute to PV A-frags via shfl ----
            uint pu[4][2];
            #pragma unroll
            for (int kb = 0; kb < 4; kb++)
                #pragma unroll
                for (int w2 = 0; w2 < 2; w2++) {
                    union { __hip_bfloat16 b[2]; uint u; } cv;
                    cv.b[0] = __float2bfloat16(p[kb][2 * w2]);
                    cv.b[1] = __float2bfloat16(p[kb][2 * w2 + 1]);
                    pu[kb][w2] = cv.u;
                }
            union { uint u[4]; bf16x8 v; } pa0, pa1;
            #pragma unroll
            for (int ww = 0; ww < 4; ww++) {
                int src = ((lg & 1) * 2 + (ww >> 1)) * 16 + li;
                uint a0 = (uint)__shfl((int)pu[0][ww & 1], src);
                uint a1 = (uint)__shfl((int)pu[1][ww & 1], src);
                uint b0 = (uint)__shfl((int)pu[2][ww & 1], src);
                uint b1 = (uint)__shfl((int)pu[3][ww & 1], src);
                pa0.u[ww] = (lg >> 1) ? a1 : a0;
                pa1.u[ww] = (lg >> 1) ? b1 : b0;
            }

            // ---- O += P V ----
            __builtin_amdgcn_s_setprio(1);
            #pragma unroll
            for (int vb = 0; vb < 4; vb++) {
                int d = vb * 16 + li;
                int vsw = ((d & 7) << 4) ^ ((vb & 3) << 5);
                bf16x8 vf0 = *(const bf16x8*)(VtB + d * 128 + ((lg * 16) ^ vsw));
                bf16x8 vf1 = *(const bf16x8*)(VtB + d * 128 + ((64 + lg * 16) ^ vsw));
                acc_o[vb] = __builtin_amdgcn_mfma_f32_16x16x32_bf16(pa0.v, vf0, acc_o[vb], 0, 0, 0);
                acc_o[vb] = __builtin_amdgcn_mfma_f32_16x16x32_bf16(pa1.v, vf1, acc_o[vb], 0, 0, 0);
            }
            __builtin_amdgcn_s_setprio(0);
        }
        __syncthreads();
    }

    if (nch == 1) {
        // single chunk: normalize and write output directly
        float lr[4];
        #pragma unroll
        for (int r = 0; r < 4; r++) lr[r] = 1.0f / __shfl(l, lg * 4 + r);
        #pragma unroll
        for (int r = 0; r < 4; r++) {
            int row = qt * 64 + w * 16 + lg * 4 + r;
            #pragma unroll
            for (int vb = 0; vb < 4; vb++)
                ao[(size_t)row * DIM + h * HD + vb * 16 + li] = __float2bfloat16(acc_o[vb][r] * lr[r]);
        }
    } else {
        // write unnormalized partial + (m, l); fully-masked rows carry m=-1e30 -> weight 0
        size_t ob = ((size_t)(c * 64 + qt) * HEADS + h) * 4096;
        #pragma unroll
        for (int r = 0; r < 4; r++) {
            int row = w * 16 + lg * 4 + r;
            #pragma unroll
            for (int vb = 0; vb < 4; vb++)
                opart[ob + (size_t)row * 64 + vb * 16 + li] = acc_o[vb][r];
        }
        if (lg == 0) {
            size_t mb = ((size_t)(c * 64 + qt) * HEADS + h) * 128;
            mlpart[mb + w * 16 + li] = m;
            mlpart[mb + 64 + w * 16 + li] = l;
        }
    }
}

// ---------------- merge split-K partials ----------------
__global__ __launch_bounds__(256) void k_merge(const int* __restrict__ kv_end,
                                               const float* __restrict__ opart,
                                               const float* __restrict__ mlpart,
                                               __hip_bfloat16* __restrict__ ao) {
    int qt = blockIdx.x, h = blockIdx.y;
    int kmaxf = kv_end[qt * 64 + 63];
    int nch = (kmaxf + CHUNK - 1) / CHUNK;
    if (nch == 1) return;                    // k_attn wrote ao directly
    int t = threadIdx.x;
    int row = t >> 2, d0 = (t & 3) * 16;

    float mc[MAXCH], lc[MAXCH];
    float mstar = -1e30f;
    for (int c = 0; c < nch; c++) {
        size_t mb = ((size_t)(c * 64 + qt) * HEADS + h) * 128;
        mc[c] = mlpart[mb + row];
        lc[c] = mlpart[mb + 64 + row];
        mstar = fmaxf(mstar, mc[c]);
    }
    float wc[MAXCH];
    float lsum = 0.f;
    for (int c = 0; c < nch; c++) { wc[c] = exp2f(mc[c] - mstar); lsum += lc[c] * wc[c]; }
    float inv = 1.0f / lsum;

    #pragma unroll
    for (int g = 0; g < 4; g++) {
        float4 acc = {0.f, 0.f, 0.f, 0.f};
        for (int c = 0; c < nch; c++) {
            const float4 v = *(const float4*)(opart +
                ((size_t)(c * 64 + qt) * HEADS + h) * 4096 + (size_t)row * 64 + d0 + g * 4);
            acc.x += v.x * wc[c]; acc.y += v.y * wc[c];
            acc.z += v.z * wc[c]; acc.w += v.w * wc[c];
        }
        __hip_bfloat16* op = ao + (size_t)(qt * 64 + row) * DIM + h * HD + d0 + g * 4;
        op[0] = __float2bfloat16(acc.x * inv);
        op[1] = __float2bfloat16(acc.y * inv);
        op[2] = __float2bfloat16(acc.z * inv);
        op[3] = __float2bfloat16(acc.w * inv);
    }
}

extern "C" void kernel_launch(void* const* d_in, const int* in_sizes, int n_in,
                              void* d_out, int out_size, void* d_ws, size_t ws_size,
                              hipStream_t stream) {
    const float* emb   = (const float*)d_in[0];
    const float* normw = (const float*)d_in[1];
    const float* Wq    = (const float*)d_in[2];
    const float* Wk    = (const float*)d_in[3];
    const float* Wv    = (const float*)d_in[4];
    const float* Wo    = (const float*)d_in[5];
    const int*   gidx  = (const int*)d_in[7];
    const int*   sids  = (const int*)d_in[8];
    float* out = (float*)d_out;

    const size_t M4 = (size_t)NTOK * DIM;
    const size_t M1 = (size_t)DIM * DIM;
    __hip_bfloat16* xnb = (__hip_bfloat16*)d_ws;             // 4M
    __hip_bfloat16* wqb = xnb + M4;                          // 1M x4
    __hip_bfloat16* wkb = wqb + M1;
    __hip_bfloat16* wvb = wkb + M1;
    __hip_bfloat16* wob = wvb + M1;
    __hip_bfloat16* qb  = wob + M1;                          // 4M x3
    __hip_bfloat16* kb  = qb + M4;
    __hip_bfloat16* vb  = kb + M4;
    __hip_bfloat16* aob = vb + M4;                           // 4M
    float* sint = (float*)(aob + M4);                        // [4096][32]
    float* cost = sint + (size_t)NTOK * 32;
    int*   kvend = (int*)(cost + (size_t)NTOK * 32);         // [4096]
    float* opart = (float*)(kvend + NTOK);                   // [4][64][16][64][64] f32 = 64MB
    float* mlpart = opart + (size_t)MAXCH * 64 * HEADS * 4096;  // [4][64][16][2][64] f32

    hipLaunchKernelGGL(k_rmsnorm, dim3(NTOK), dim3(256), 0, stream, emb, normw, xnb);
    hipLaunchKernelGGL(k_w2bf, dim3(M1 / 1024, 4), dim3(256), 0, stream,
                       Wq, Wk, Wv, Wo, wqb, wkb, wvb, wob);
    hipLaunchKernelGGL(k_prep, dim3((NTOK + 255) / 256), dim3(256), 0, stream,
                       sids, gidx, kvend, sint, cost);
    hipLaunchKernelGGL(k_qkv, dim3(NTOK / 128, DIM / 128, 3), dim3(256), 0, stream,
                       xnb, wqb, wkb, wvb, sint, cost, qb, kb, vb);
    hipLaunchKernelGGL(k_attn, dim3(NTOK / 64, HEADS, MAXCH), dim3(256), 0, stream,
                       qb, kb, vb, kvend, opart, mlpart, aob);
    hipLaunchKernelGGL(k_merge, dim3(NTOK / 64, HEADS), dim3(256), 0, stream,
                       kvend, opart, mlpart, aob);
    hipLaunchKernelGGL(k_wo, dim3(NTOK / 128, DIM / 128), dim3(256), 0, stream,
                       aob, wob, out);
}